// Round 2
// baseline (269.370 us; speedup 1.0000x reference)
//
#include <hip/hip_runtime.h>
#include <hip/hip_bf16.h>
#include <stdint.h>

// Problem constants (SpatialDecoder: B=128, N=1024, DM=64, S=2, D_IN=68)
#define NB 128
#define NN 1024
#define NDM 64

typedef __bf16 bf16;
typedef __bf16 bf16x8_t __attribute__((ext_vector_type(8)));
typedef __bf16 bf16x4_t __attribute__((ext_vector_type(4)));
typedef float f32x4 __attribute__((ext_vector_type(4)));

// ---------------------------------------------------------------------------
// k0: fold W_gc @ W_in -> Wy [128 x 68]; by[so] = W_gc_s @ b_in;
//     HB[o] = b_out[o] + W_out[o, :64] . b_gc;  W1B[o*64+c] = bf16(W_out[o,c])
// ---------------------------------------------------------------------------
__global__ __launch_bounds__(256) void k_prep_w(
    const float* __restrict__ W_in, const float* __restrict__ b_in,
    const float* __restrict__ W_gc, const float* __restrict__ b_gc,
    const float* __restrict__ W_out, const float* __restrict__ b_out,
    float* __restrict__ Wy, float* __restrict__ by,
    float* __restrict__ HB, bf16* __restrict__ W1B) {
  int i = blockIdx.x * 256 + threadIdx.x;
  if (i < 8704) {  // Wy: 128 x 68
    int so = i / 68, cp = i % 68;
    int s = so >> 6, o = so & 63;
    float acc = 0.f;
    for (int c = 0; c < 64; ++c) acc += W_gc[o * 128 + s * 64 + c] * W_in[c * 68 + cp];
    Wy[i] = acc;
  } else if (i < 8832) {  // by: 128
    int so = i - 8704;
    int s = so >> 6, o = so & 63;
    float acc = 0.f;
    for (int c = 0; c < 64; ++c) acc += W_gc[o * 128 + s * 64 + c] * b_in[c];
    by[so] = acc;
  } else if (i < 8896) {  // HB: 64
    int o = i - 8832;
    float acc = b_out[o];
    for (int c = 0; c < 64; ++c) acc += W_out[o * 128 + c] * b_gc[c];
    HB[o] = acc;
  } else if (i < 12992) {  // W1B: 64x64 bf16
    int j = i - 8896;
    int o = j >> 6, c = j & 63;
    W1B[j] = (bf16)W_out[o * 128 + c];
  }
}

// ---------------------------------------------------------------------------
// k2: adj f32 -> bf16 (2M elements), float4-vectorized
// ---------------------------------------------------------------------------
__global__ __launch_bounds__(256) void k_adj_bf16(
    const float* __restrict__ adj, bf16* __restrict__ adjb) {
  int i = blockIdx.x * 256 + threadIdx.x;  // one float4 per thread
  float4 v = reinterpret_cast<const float4*>(adj)[i];
  bf16x4_t r;
  r.x = (bf16)v.x; r.y = (bf16)v.y; r.z = (bf16)v.z; r.w = (bf16)v.w;
  reinterpret_cast<bf16x4_t*>(adjb)[i] = r;
}

// ---------------------------------------------------------------------------
// k1: grid (N/256, 3, B).
//  y<2 : Y[b, o, s, v] = by[so] + sum_{c'<68} Wy[so,c'] * inp[b,c',v]  (bf16)
//  y==2: hout (pre-PReLU h-half of W_out) written into out2[b, 0..63, v] (f32):
//          hout[b,o,v] = HB[o] + sum_c W_out[o,64+c]*h[b,c,v]
//        + h passthrough: out2[b,64+c,v] = h[b,c,v]
//        + hread[b,v]    = sum_c W_read[64+c]*h[b,c,v]
// Block: 256 thr; wave og owns 16 outputs; lane owns 4 consecutive v.
// ---------------------------------------------------------------------------
__global__ __launch_bounds__(256) void k_build_y(
    const float* __restrict__ x, const float* __restrict__ m, const float* __restrict__ u,
    const float* __restrict__ h, const float* __restrict__ Wy, const float* __restrict__ by,
    const float* __restrict__ HB, const float* __restrict__ W_out,
    const float* __restrict__ W_read,
    bf16* __restrict__ Y, float* __restrict__ out2, float* __restrict__ hread) {
  __shared__ __align__(16) float Wt[68 * 64];  // transposed: Wt[c'][o]
  __shared__ float bl[64];
  __shared__ float Wrh[64];
  const int t = threadIdx.x;
  const int s = blockIdx.y, b = blockIdx.z;
  const bool hpath = (s == 2);
  if (!hpath) {
    for (int i = t; i < 68 * 64; i += 256) {
      int cp = i >> 6, o = i & 63;
      Wt[i] = Wy[(s * 64 + o) * 68 + cp];
    }
    if (t < 64) bl[t] = by[s * 64 + t];
  } else {
    for (int i = t; i < 64 * 64; i += 256) {
      int c = i >> 6, o = i & 63;
      Wt[i] = W_out[o * 128 + 64 + c];
    }
    if (t < 64) { bl[t] = HB[t]; Wrh[t] = W_read[64 + t]; }
  }
  __syncthreads();
  const int og = t >> 6, lane = t & 63;
  const int vb = blockIdx.x * 256;

  float acc[16][4];
#pragma unroll
  for (int oi = 0; oi < 16; ++oi) {
    float bv = bl[og * 16 + oi];
    acc[oi][0] = bv; acc[oi][1] = bv; acc[oi][2] = bv; acc[oi][3] = bv;
  }
  float hracc[4] = {0.f, 0.f, 0.f, 0.f};

  auto doCh = [&](int cp, const float4 v) {
    const float4* wr = reinterpret_cast<const float4*>(&Wt[cp * 64 + og * 16]);
    float wv[16];
    *reinterpret_cast<float4*>(&wv[0])  = wr[0];
    *reinterpret_cast<float4*>(&wv[4])  = wr[1];
    *reinterpret_cast<float4*>(&wv[8])  = wr[2];
    *reinterpret_cast<float4*>(&wv[12]) = wr[3];
#pragma unroll
    for (int oi = 0; oi < 16; ++oi) {
      acc[oi][0] += wv[oi] * v.x;
      acc[oi][1] += wv[oi] * v.y;
      acc[oi][2] += wv[oi] * v.z;
      acc[oi][3] += wv[oi] * v.w;
    }
  };

  if (!hpath) {
    doCh(0, *reinterpret_cast<const float4*>(x + b * NN + vb + lane * 4));
    doCh(1, *reinterpret_cast<const float4*>(m + b * NN + vb + lane * 4));
    doCh(2, *reinterpret_cast<const float4*>(u + (b * 2 + 0) * NN + vb + lane * 4));
    doCh(3, *reinterpret_cast<const float4*>(u + (b * 2 + 1) * NN + vb + lane * 4));
    for (int c = 0; c < 64; ++c)
      doCh(4 + c, *reinterpret_cast<const float4*>(h + ((size_t)(b * 64 + c)) * NN + vb + lane * 4));
#pragma unroll
    for (int oi = 0; oi < 16; ++oi) {
      bf16x4_t r;
      r.x = (bf16)acc[oi][0]; r.y = (bf16)acc[oi][1];
      r.z = (bf16)acc[oi][2]; r.w = (bf16)acc[oi][3];
      size_t row = (size_t)(b * 64 + og * 16 + oi);
      *reinterpret_cast<bf16x4_t*>(&Y[row * 2048 + s * 1024 + vb + lane * 4]) = r;
    }
  } else {
    for (int c = 0; c < 64; ++c) {
      float4 hv = *reinterpret_cast<const float4*>(h + ((size_t)(b * 64 + c)) * NN + vb + lane * 4);
      doCh(c, hv);
      if (og == 0) {  // h passthrough (exact f32) + read h-part
        *reinterpret_cast<float4*>(&out2[(size_t)(b * 128 + 64 + c) * NN + vb + lane * 4]) = hv;
        float wrh = Wrh[c];
        hracc[0] += wrh * hv.x; hracc[1] += wrh * hv.y;
        hracc[2] += wrh * hv.z; hracc[3] += wrh * hv.w;
      }
    }
#pragma unroll
    for (int oi = 0; oi < 16; ++oi) {
      float4 st;
      st.x = acc[oi][0]; st.y = acc[oi][1]; st.z = acc[oi][2]; st.w = acc[oi][3];
      *reinterpret_cast<float4*>(&out2[(size_t)(b * 128 + og * 16 + oi) * NN + vb + lane * 4]) = st;
    }
    if (og == 0) {
      float4 st;
      st.x = hracc[0]; st.y = hracc[1]; st.z = hracc[2]; st.w = hracc[3];
      *reinterpret_cast<float4*>(&hread[(size_t)b * NN + vb + lane * 4]) = st;
    }
  }
}

// ---------------------------------------------------------------------------
// k3: fused GEMM + decoder epilogue.
// Main loop (m97 structure): gc[(b,c), w] = sum_k Y[(b,c),k] * ADJB[w,k]
//   128x128 tile, BK=32, 256 thr (2x2 waves of 64x64), global_load_lds w=16.
// Phase 2: gc tile -> LDS bf16 [b2][w(128)][c(64) pad 72]; per-wave MFMA
//   out[o,w] = W1 @ gc  (K=64), then epilogue:
//   val = acc + out2[b, o, w]  (hout from k_build_y, f32)
//   val = PReLU(val); out2[b,o,w] = val
//   out0[b,w] = b_read + hread[b,w] + sum_o Wr[o]*val  (shfl_xor reduce)
// Grid: (64, 8). Rows rowA..rowA+127 = batches {2bx, 2bx+1} x 64 channels.
// ---------------------------------------------------------------------------
__global__ __launch_bounds__(256) void k_gemm(
    const bf16* __restrict__ Y, const bf16* __restrict__ ADJB,
    const bf16* __restrict__ W1B, const float* __restrict__ W_read,
    const float* __restrict__ b_read, const float* __restrict__ prelu_w,
    const float* __restrict__ hread, float* __restrict__ out0, float* __restrict__ out2) {
  __shared__ __align__(16) union SMem {
    struct { bf16 As[128 * 32]; bf16 Bs[128 * 32]; } st;   // main loop staging (16 KB)
    bf16 gcs[2 * 128 * 72];                                // phase 2 gc tile (36 KB)
  } sm;
  __shared__ __align__(16) bf16 W1s[64 * 72];              // W1[o][c] padded (9 KB)
  __shared__ float Wrs[64];

  const int t = threadIdx.x;
  const int wave = t >> 6, lane = t & 63;
  const int rowA = blockIdx.x * 128;
  const int colB = blockIdx.y * 128;
  const int wm = (wave & 1) * 64, wn = (wave >> 1) * 64;
  const int fr = lane & 15;         // fragment row (m / n)
  const int fk = (lane >> 4) * 8;   // fragment k offset

  // persistent weight staging
  for (int i = t; i < 4096; i += 256) W1s[(i >> 6) * 72 + (i & 63)] = W1B[i];
  if (t < 64) Wrs[t] = W_read[t];
  const float pw = prelu_w[0];
  const float br = b_read[0];

  f32x4 acc[4][4];
  const f32x4 zero = {0.f, 0.f, 0.f, 0.f};
#pragma unroll
  for (int i = 0; i < 4; ++i)
#pragma unroll
    for (int j = 0; j < 4; ++j) acc[i][j] = zero;

  const int c0 = wave * 128 + lane;   // staging chunk (16B each)
  const int c1 = c0 + 64;
  __syncthreads();  // W1s/Wrs visible; also before first staging

  for (int k0 = 0; k0 < 2048; k0 += 32) {
    const int s = k0 >> 10, v0 = k0 & 1023;
    {
      const bf16* g0 = Y + (size_t)(rowA + (c0 >> 2)) * 2048 + k0 + (c0 & 3) * 8;
      const bf16* g1 = Y + (size_t)(rowA + (c1 >> 2)) * 2048 + k0 + (c1 & 3) * 8;
      __builtin_amdgcn_global_load_lds((const uint32_t*)g0, (uint32_t*)&sm.st.As[c0 * 8], 16, 0, 0);
      __builtin_amdgcn_global_load_lds((const uint32_t*)g1, (uint32_t*)&sm.st.As[c1 * 8], 16, 0, 0);
      const bf16* bbase = ADJB + (size_t)s * (1024 * 1024) + v0;
      const bf16* gb0 = bbase + (size_t)(colB + (c0 >> 2)) * 1024 + (c0 & 3) * 8;
      const bf16* gb1 = bbase + (size_t)(colB + (c1 >> 2)) * 1024 + (c1 & 3) * 8;
      __builtin_amdgcn_global_load_lds((const uint32_t*)gb0, (uint32_t*)&sm.st.Bs[c0 * 8], 16, 0, 0);
      __builtin_amdgcn_global_load_lds((const uint32_t*)gb1, (uint32_t*)&sm.st.Bs[c1 * 8], 16, 0, 0);
    }
    __syncthreads();
    bf16x8_t af[4], bfr[4];
#pragma unroll
    for (int i = 0; i < 4; ++i)
      af[i] = *reinterpret_cast<const bf16x8_t*>(&sm.st.As[(wm + i * 16 + fr) * 32 + fk]);
#pragma unroll
    for (int i = 0; i < 4; ++i)
      bfr[i] = *reinterpret_cast<const bf16x8_t*>(&sm.st.Bs[(wn + i * 16 + fr) * 32 + fk]);
#pragma unroll
    for (int i = 0; i < 4; ++i)
#pragma unroll
      for (int j = 0; j < 4; ++j)
        acc[i][j] = __builtin_amdgcn_mfma_f32_16x16x32_bf16(af[i], bfr[j], acc[i][j], 0, 0, 0);
    __syncthreads();
  }

  // ---- phase 2: gc tile -> LDS bf16, layout [b2][w_local][c] pad 72 ----
  {
    const int b2w = wm >> 6;  // which batch half this wave's rows belong to
#pragma unroll
    for (int i = 0; i < 4; ++i) {
      const int cc0 = i * 16 + (lane >> 4) * 4;  // channel base (rows minus wm)
#pragma unroll
      for (int j = 0; j < 4; ++j) {
        const int wl = wn + j * 16 + (lane & 15);
        bf16x4_t r;
        r.x = (bf16)acc[i][j][0]; r.y = (bf16)acc[i][j][1];
        r.z = (bf16)acc[i][j][2]; r.w = (bf16)acc[i][j][3];
        *reinterpret_cast<bf16x4_t*>(&sm.gcs[b2w * 9216 + wl * 72 + cc0]) = r;
      }
    }
  }
  __syncthreads();

  // per-wave: b2 = wave>>1, column half jh = wave&1
  const int b2 = wave >> 1, jh = wave & 1;
  const int b = blockIdx.x * 2 + b2;

  f32x4 acc2[4][4];
#pragma unroll
  for (int i = 0; i < 4; ++i)
#pragma unroll
    for (int j = 0; j < 4; ++j) acc2[i][j] = zero;

#pragma unroll
  for (int k2 = 0; k2 < 64; k2 += 32) {
    bf16x8_t af2[4], bf2[4];
#pragma unroll
    for (int i = 0; i < 4; ++i)
      af2[i] = *reinterpret_cast<const bf16x8_t*>(&W1s[(i * 16 + fr) * 72 + k2 + fk]);
#pragma unroll
    for (int j = 0; j < 4; ++j)
      bf2[j] = *reinterpret_cast<const bf16x8_t*>(&sm.gcs[b2 * 9216 + (jh * 64 + j * 16 + fr) * 72 + k2 + fk]);
#pragma unroll
    for (int i = 0; i < 4; ++i)
#pragma unroll
      for (int j = 0; j < 4; ++j)
        acc2[i][j] = __builtin_amdgcn_mfma_f32_16x16x32_bf16(af2[i], bf2[j], acc2[i][j], 0, 0, 0);
  }

  // epilogue: add hout (in out2), PReLU, write out2, reduce read output
  float rd[4] = {0.f, 0.f, 0.f, 0.f};
#pragma unroll
  for (int i = 0; i < 4; ++i) {
    const int ob = i * 16 + (lane >> 4) * 4;
#pragma unroll
    for (int r = 0; r < 4; ++r) {
      const int o = ob + r;
      const float wr = Wrs[o];
#pragma unroll
      for (int j = 0; j < 4; ++j) {
        const int wg = colB + jh * 64 + j * 16 + (lane & 15);
        float* p = &out2[(size_t)(b * 128 + o) * 1024 + wg];
        float val = acc2[i][j][r] + *p;
        val = val >= 0.f ? val : pw * val;
        *p = val;
        rd[j] += wr * val;
      }
    }
  }
#pragma unroll
  for (int j = 0; j < 4; ++j) {
    rd[j] += __shfl_xor(rd[j], 16, 64);
    rd[j] += __shfl_xor(rd[j], 32, 64);
  }
  if (lane < 16) {
#pragma unroll
    for (int j = 0; j < 4; ++j) {
      const int wg = colB + jh * 64 + j * 16 + lane;
      out0[(size_t)b * 1024 + wg] = rd[j] + hread[(size_t)b * 1024 + wg] + br;
    }
  }
}

// ---------------------------------------------------------------------------
extern "C" void kernel_launch(void* const* d_in, const int* in_sizes, int n_in,
                              void* d_out, int out_size, void* d_ws, size_t ws_size,
                              hipStream_t stream) {
  (void)in_sizes; (void)n_in; (void)out_size; (void)ws_size;
  const float* x       = (const float*)d_in[0];
  const float* m       = (const float*)d_in[1];
  const float* u       = (const float*)d_in[2];
  const float* h       = (const float*)d_in[3];
  const float* adj     = (const float*)d_in[4];
  const float* W_in    = (const float*)d_in[5];
  const float* b_in    = (const float*)d_in[6];
  const float* W_gc    = (const float*)d_in[7];
  const float* b_gc    = (const float*)d_in[8];
  const float* W_out   = (const float*)d_in[9];
  const float* b_out   = (const float*)d_in[10];
  const float* W_read  = (const float*)d_in[11];
  const float* b_read  = (const float*)d_in[12];
  const float* prelu_w = (const float*)d_in[13];

  char* ws = (char*)d_ws;
  bf16*  Y     = (bf16*)(ws);                      // 8192*2048*2   = 33554432 B
  bf16*  ADJB  = (bf16*)(ws + 33554432);           // 2*1024*1024*2 =  4194304 B
  float* HREAD = (float*)(ws + 37748736);          // 128*1024*4    =   524288 B
  float* WY    = (float*)(ws + 38273024);          // 128*68*4      =    34816 B
  float* BY    = (float*)(ws + 38307840);          // 128*4         =      512 B
  float* HB    = (float*)(ws + 38308352);          // 64*4          =      256 B
  bf16*  W1B   = (bf16*)(ws + 38308608);           // 64*64*2       =     8192 B

  float* out0 = (float*)d_out;           // read  [B,1,N]  = 131072 f32
  float* out2 = out0 + 131072;           // out2  [B,128,N] f32

  hipLaunchKernelGGL(k_prep_w,  dim3(51),         dim3(256), 0, stream,
                     W_in, b_in, W_gc, b_gc, W_out, b_out, WY, BY, HB, W1B);
  hipLaunchKernelGGL(k_adj_bf16,dim3(2048),       dim3(256), 0, stream, adj, ADJB);
  hipLaunchKernelGGL(k_build_y, dim3(4, 3, 128),  dim3(256), 0, stream,
                     x, m, u, h, WY, BY, HB, W_out, W_read, Y, out2, HREAD);
  hipLaunchKernelGGL(k_gemm,    dim3(64, 8),      dim3(256), 0, stream,
                     Y, ADJB, W1B, W_read, b_read, prelu_w, HREAD, out0, out2);
}

// Round 3
// 223.457 us; speedup vs baseline: 1.2055x; 1.2055x over previous
//
#include <hip/hip_runtime.h>
#include <hip/hip_bf16.h>
#include <stdint.h>

// Problem constants (SpatialDecoder: B=128, N=1024, DM=64, S=2, D_IN=68)
#define NB 128
#define NN 1024
#define NDM 64

typedef __bf16 bf16;
typedef __bf16 bf16x8_t __attribute__((ext_vector_type(8)));
typedef __bf16 bf16x4_t __attribute__((ext_vector_type(4)));
typedef __bf16 bf16x2_t __attribute__((ext_vector_type(2)));
typedef float f32x4 __attribute__((ext_vector_type(4)));

// ---------------------------------------------------------------------------
// k0: weight prep.
//  WyT[s][cp][o] = sum_c W_gc[o, s*64+c] * W_in[c, cp]   (transposed fold)
//  by[so]       = W_gc_s @ b_in
//  HB[o]        = b_out[o] + W_out[o,:64] . b_gc
//  W1B[o*64+c]  = bf16(W_out[o,c])          (gc half, for GEMM epilogue MFMA)
//  W2T[c*64+o]  = W_out[o,64+c]             (h half, transposed f32)
// ---------------------------------------------------------------------------
__global__ __launch_bounds__(256) void k_prep_w(
    const float* __restrict__ W_in, const float* __restrict__ b_in,
    const float* __restrict__ W_gc, const float* __restrict__ b_gc,
    const float* __restrict__ W_out, const float* __restrict__ b_out,
    float* __restrict__ WyT, float* __restrict__ by,
    float* __restrict__ HB, bf16* __restrict__ W1B, float* __restrict__ W2T) {
  int i = blockIdx.x * 256 + threadIdx.x;
  if (i < 8704) {  // WyT: [2][68][64]
    int o = i & 63, sc = i >> 6;
    int s = sc / 68, cp = sc % 68;
    float acc = 0.f;
    for (int c = 0; c < 64; ++c) acc += W_gc[o * 128 + s * 64 + c] * W_in[c * 68 + cp];
    WyT[i] = acc;
  } else if (i < 8832) {  // by: 128
    int so = i - 8704;
    int s = so >> 6, o = so & 63;
    float acc = 0.f;
    for (int c = 0; c < 64; ++c) acc += W_gc[o * 128 + s * 64 + c] * b_in[c];
    by[so] = acc;
  } else if (i < 8896) {  // HB: 64
    int o = i - 8832;
    float acc = b_out[o];
    for (int c = 0; c < 64; ++c) acc += W_out[o * 128 + c] * b_gc[c];
    HB[o] = acc;
  } else if (i < 12992) {  // W1B: 64x64 bf16
    int j = i - 8896;
    int o = j >> 6, c = j & 63;
    W1B[j] = (bf16)W_out[o * 128 + c];
  } else if (i < 17088) {  // W2T: [c][o] f32
    int j = i - 12992;
    int c = j >> 6, o = j & 63;
    W2T[j] = W_out[o * 128 + 64 + c];
  }
}

// ---------------------------------------------------------------------------
// k2: adj f32 -> bf16 (2M elements), float4-vectorized
// ---------------------------------------------------------------------------
__global__ __launch_bounds__(256) void k_adj_bf16(
    const float* __restrict__ adj, bf16* __restrict__ adjb) {
  int i = blockIdx.x * 256 + threadIdx.x;  // one float4 per thread
  float4 v = reinterpret_cast<const float4*>(adj)[i];
  bf16x4_t r;
  r.x = (bf16)v.x; r.y = (bf16)v.y; r.z = (bf16)v.z; r.w = (bf16)v.w;
  reinterpret_cast<bf16x4_t*>(adjb)[i] = r;
}

// ---------------------------------------------------------------------------
// k1: grid (N/128=8, 3, B).  LDS-staged via global_load_lds (width 16).
//  s<2 : Y[b, o, s, v] = by[so] + sum_{cp<68} WyT[s,cp,o] * X[cp,v]   (bf16)
//        X rows: [x, m, u0, u1, h0..h63]
//  s==2: hout[b,o,v] = HB[o] + sum_c W2T[c,o]*h[c,v]  -> out2[b, o, v] (f32)
//        + h passthrough out2[b,64+c,v] = h[c,v]
//        + hread[b,v] = sum_c W_read[64+c]*h[c,v]
// Block: 256 thr; wave og owns 16 outputs; lane owns 2 consecutive v.
// ---------------------------------------------------------------------------
__global__ __launch_bounds__(256) void k_build_y(
    const float* __restrict__ x, const float* __restrict__ m, const float* __restrict__ u,
    const float* __restrict__ h, const float* __restrict__ WyT, const float* __restrict__ by,
    const float* __restrict__ HB, const float* __restrict__ W2T,
    const float* __restrict__ W_read,
    bf16* __restrict__ Y, float* __restrict__ out2, float* __restrict__ hread) {
  __shared__ __align__(16) float Xs[68 * 128];   // 34816 B, row = channel
  __shared__ __align__(16) float Wt[68 * 64];    // 17408 B, Wt[cp][o]
  __shared__ float bl[64];
  __shared__ float Wrh[64];
  const int t = threadIdx.x;
  const int s = blockIdx.y, b = blockIdx.z;
  const int vb = blockIdx.x * 128;
  const bool hpath = (s == 2);

  // ---- stage weights (coalesced from transposed global copies) ----
  if (!hpath) {
    for (int i = t; i < 68 * 64; i += 256) Wt[i] = WyT[s * 4352 + i];
    if (t < 64) bl[t] = by[s * 64 + t];
  } else {
    for (int i = t; i < 64 * 64; i += 256) Wt[i] = W2T[i];
    if (t < 64) { bl[t] = HB[t]; Wrh[t] = W_read[64 + t]; }
  }

  // ---- stage X tile via async global->LDS (16B chunks) ----
  // chunk i: row r = i>>5 (channel), ck = i&31 (4 floats each), 32 chunks/row
  const int nch = hpath ? 2048 : 2176;
  for (int i = t; i < nch; i += 256) {
    int r = i >> 5, ck = i & 31;
    const float* src;
    if (!hpath) {
      if (r >= 4)      src = h + (size_t)(b * 64 + (r - 4)) * NN;
      else if (r == 0) src = x + (size_t)b * NN;
      else if (r == 1) src = m + (size_t)b * NN;
      else             src = u + (size_t)(b * 2 + (r - 2)) * NN;
    } else {
      src = h + (size_t)(b * 64 + r) * NN;
    }
    __builtin_amdgcn_global_load_lds((const uint32_t*)(src + vb + ck * 4),
                                     (uint32_t*)&Xs[i * 4], 16, 0, 0);
  }
  __syncthreads();

  const int og = t >> 6, lane = t & 63;
  const int v0 = lane * 2;

  float acc[16][2];
#pragma unroll
  for (int oi = 0; oi < 16; ++oi) {
    float bv = bl[og * 16 + oi];
    acc[oi][0] = bv; acc[oi][1] = bv;
  }

  const int NCH = hpath ? 64 : 68;
#pragma unroll 2
  for (int cp = 0; cp < NCH; ++cp) {
    float2 xv = *reinterpret_cast<const float2*>(&Xs[cp * 128 + v0]);
    const float4* wr = reinterpret_cast<const float4*>(&Wt[cp * 64 + og * 16]);
    float wv[16];
    *reinterpret_cast<float4*>(&wv[0])  = wr[0];
    *reinterpret_cast<float4*>(&wv[4])  = wr[1];
    *reinterpret_cast<float4*>(&wv[8])  = wr[2];
    *reinterpret_cast<float4*>(&wv[12]) = wr[3];
#pragma unroll
    for (int oi = 0; oi < 16; ++oi) {
      acc[oi][0] += wv[oi] * xv.x;
      acc[oi][1] += wv[oi] * xv.y;
    }
  }

  if (!hpath) {
#pragma unroll
    for (int oi = 0; oi < 16; ++oi) {
      bf16x2_t r;
      r.x = (bf16)acc[oi][0]; r.y = (bf16)acc[oi][1];
      size_t row = (size_t)(b * 64 + og * 16 + oi);
      *reinterpret_cast<bf16x2_t*>(&Y[row * 2048 + s * 1024 + vb + v0]) = r;
    }
  } else {
#pragma unroll
    for (int oi = 0; oi < 16; ++oi) {
      float2 st; st.x = acc[oi][0]; st.y = acc[oi][1];
      *reinterpret_cast<float2*>(&out2[(size_t)(b * 128 + og * 16 + oi) * NN + vb + v0]) = st;
    }
    // h passthrough: rows og*16 .. og*16+15
#pragma unroll
    for (int k = 0; k < 16; ++k) {
      int c = og * 16 + k;
      float2 hv = *reinterpret_cast<const float2*>(&Xs[c * 128 + v0]);
      *reinterpret_cast<float2*>(&out2[(size_t)(b * 128 + 64 + c) * NN + vb + v0]) = hv;
    }
    if (og == 0) {
      float hr0 = 0.f, hr1 = 0.f;
      for (int c = 0; c < 64; ++c) {
        float2 xv = *reinterpret_cast<const float2*>(&Xs[c * 128 + v0]);
        float wc = Wrh[c];
        hr0 += wc * xv.x; hr1 += wc * xv.y;
      }
      float2 st; st.x = hr0; st.y = hr1;
      *reinterpret_cast<float2*>(&hread[(size_t)b * NN + vb + v0]) = st;
    }
  }
}

// ---------------------------------------------------------------------------
// k3: fused GEMM + decoder epilogue (unchanged from round 2).
// Main loop: gc[(b,c), w] = sum_k Y[(b,c),k] * ADJB[w,k]; 128x128 tile, BK=32.
// Phase 2: gc tile -> LDS bf16; per-wave MFMA out = W1 @ gc; add hout (out2),
// PReLU, write out2, reduce read output into out0.
// Grid: (64, 8).
// ---------------------------------------------------------------------------
__global__ __launch_bounds__(256) void k_gemm(
    const bf16* __restrict__ Y, const bf16* __restrict__ ADJB,
    const bf16* __restrict__ W1B, const float* __restrict__ W_read,
    const float* __restrict__ b_read, const float* __restrict__ prelu_w,
    const float* __restrict__ hread, float* __restrict__ out0, float* __restrict__ out2) {
  __shared__ __align__(16) union SMem {
    struct { bf16 As[128 * 32]; bf16 Bs[128 * 32]; } st;   // main loop staging (16 KB)
    bf16 gcs[2 * 128 * 72];                                // phase 2 gc tile (36 KB)
  } sm;
  __shared__ __align__(16) bf16 W1s[64 * 72];              // W1[o][c] padded (9 KB)
  __shared__ float Wrs[64];

  const int t = threadIdx.x;
  const int wave = t >> 6, lane = t & 63;
  const int rowA = blockIdx.x * 128;
  const int colB = blockIdx.y * 128;
  const int wm = (wave & 1) * 64, wn = (wave >> 1) * 64;
  const int fr = lane & 15;         // fragment row (m / n)
  const int fk = (lane >> 4) * 8;   // fragment k offset

  for (int i = t; i < 4096; i += 256) W1s[(i >> 6) * 72 + (i & 63)] = W1B[i];
  if (t < 64) Wrs[t] = W_read[t];
  const float pw = prelu_w[0];
  const float br = b_read[0];

  f32x4 acc[4][4];
  const f32x4 zero = {0.f, 0.f, 0.f, 0.f};
#pragma unroll
  for (int i = 0; i < 4; ++i)
#pragma unroll
    for (int j = 0; j < 4; ++j) acc[i][j] = zero;

  const int c0 = wave * 128 + lane;   // staging chunk (16B each)
  const int c1 = c0 + 64;
  __syncthreads();

  for (int k0 = 0; k0 < 2048; k0 += 32) {
    const int s = k0 >> 10, v0 = k0 & 1023;
    {
      const bf16* g0 = Y + (size_t)(rowA + (c0 >> 2)) * 2048 + k0 + (c0 & 3) * 8;
      const bf16* g1 = Y + (size_t)(rowA + (c1 >> 2)) * 2048 + k0 + (c1 & 3) * 8;
      __builtin_amdgcn_global_load_lds((const uint32_t*)g0, (uint32_t*)&sm.st.As[c0 * 8], 16, 0, 0);
      __builtin_amdgcn_global_load_lds((const uint32_t*)g1, (uint32_t*)&sm.st.As[c1 * 8], 16, 0, 0);
      const bf16* bbase = ADJB + (size_t)s * (1024 * 1024) + v0;
      const bf16* gb0 = bbase + (size_t)(colB + (c0 >> 2)) * 1024 + (c0 & 3) * 8;
      const bf16* gb1 = bbase + (size_t)(colB + (c1 >> 2)) * 1024 + (c1 & 3) * 8;
      __builtin_amdgcn_global_load_lds((const uint32_t*)gb0, (uint32_t*)&sm.st.Bs[c0 * 8], 16, 0, 0);
      __builtin_amdgcn_global_load_lds((const uint32_t*)gb1, (uint32_t*)&sm.st.Bs[c1 * 8], 16, 0, 0);
    }
    __syncthreads();
    bf16x8_t af[4], bfr[4];
#pragma unroll
    for (int i = 0; i < 4; ++i)
      af[i] = *reinterpret_cast<const bf16x8_t*>(&sm.st.As[(wm + i * 16 + fr) * 32 + fk]);
#pragma unroll
    for (int i = 0; i < 4; ++i)
      bfr[i] = *reinterpret_cast<const bf16x8_t*>(&sm.st.Bs[(wn + i * 16 + fr) * 32 + fk]);
#pragma unroll
    for (int i = 0; i < 4; ++i)
#pragma unroll
      for (int j = 0; j < 4; ++j)
        acc[i][j] = __builtin_amdgcn_mfma_f32_16x16x32_bf16(af[i], bfr[j], acc[i][j], 0, 0, 0);
    __syncthreads();
  }

  // ---- phase 2: gc tile -> LDS bf16, layout [b2][w_local][c] pad 72 ----
  {
    const int b2w = wm >> 6;
#pragma unroll
    for (int i = 0; i < 4; ++i) {
      const int cc0 = i * 16 + (lane >> 4) * 4;
#pragma unroll
      for (int j = 0; j < 4; ++j) {
        const int wl = wn + j * 16 + (lane & 15);
        bf16x4_t r;
        r.x = (bf16)acc[i][j][0]; r.y = (bf16)acc[i][j][1];
        r.z = (bf16)acc[i][j][2]; r.w = (bf16)acc[i][j][3];
        *reinterpret_cast<bf16x4_t*>(&sm.gcs[b2w * 9216 + wl * 72 + cc0]) = r;
      }
    }
  }
  __syncthreads();

  const int b2 = wave >> 1, jh = wave & 1;
  const int b = blockIdx.x * 2 + b2;

  f32x4 acc2[4][4];
#pragma unroll
  for (int i = 0; i < 4; ++i)
#pragma unroll
    for (int j = 0; j < 4; ++j) acc2[i][j] = zero;

#pragma unroll
  for (int k2 = 0; k2 < 64; k2 += 32) {
    bf16x8_t af2[4], bf2[4];
#pragma unroll
    for (int i = 0; i < 4; ++i)
      af2[i] = *reinterpret_cast<const bf16x8_t*>(&W1s[(i * 16 + fr) * 72 + k2 + fk]);
#pragma unroll
    for (int j = 0; j < 4; ++j)
      bf2[j] = *reinterpret_cast<const bf16x8_t*>(&sm.gcs[b2 * 9216 + (jh * 64 + j * 16 + fr) * 72 + k2 + fk]);
#pragma unroll
    for (int i = 0; i < 4; ++i)
#pragma unroll
      for (int j = 0; j < 4; ++j)
        acc2[i][j] = __builtin_amdgcn_mfma_f32_16x16x32_bf16(af2[i], bf2[j], acc2[i][j], 0, 0, 0);
  }

  float rd[4] = {0.f, 0.f, 0.f, 0.f};
#pragma unroll
  for (int i = 0; i < 4; ++i) {
    const int ob = i * 16 + (lane >> 4) * 4;
#pragma unroll
    for (int r = 0; r < 4; ++r) {
      const int o = ob + r;
      const float wr = Wrs[o];
#pragma unroll
      for (int j = 0; j < 4; ++j) {
        const int wg = colB + jh * 64 + j * 16 + (lane & 15);
        float* p = &out2[(size_t)(b * 128 + o) * 1024 + wg];
        float val = acc2[i][j][r] + *p;
        val = val >= 0.f ? val : pw * val;
        *p = val;
        rd[j] += wr * val;
      }
    }
  }
#pragma unroll
  for (int j = 0; j < 4; ++j) {
    rd[j] += __shfl_xor(rd[j], 16, 64);
    rd[j] += __shfl_xor(rd[j], 32, 64);
  }
  if (lane < 16) {
#pragma unroll
    for (int j = 0; j < 4; ++j) {
      const int wg = colB + jh * 64 + j * 16 + lane;
      out0[(size_t)b * 1024 + wg] = rd[j] + hread[(size_t)b * 1024 + wg] + br;
    }
  }
}

// ---------------------------------------------------------------------------
extern "C" void kernel_launch(void* const* d_in, const int* in_sizes, int n_in,
                              void* d_out, int out_size, void* d_ws, size_t ws_size,
                              hipStream_t stream) {
  (void)in_sizes; (void)n_in; (void)out_size; (void)ws_size;
  const float* x       = (const float*)d_in[0];
  const float* m       = (const float*)d_in[1];
  const float* u       = (const float*)d_in[2];
  const float* h       = (const float*)d_in[3];
  const float* adj     = (const float*)d_in[4];
  const float* W_in    = (const float*)d_in[5];
  const float* b_in    = (const float*)d_in[6];
  const float* W_gc    = (const float*)d_in[7];
  const float* b_gc    = (const float*)d_in[8];
  const float* W_out   = (const float*)d_in[9];
  const float* b_out   = (const float*)d_in[10];
  const float* W_read  = (const float*)d_in[11];
  const float* b_read  = (const float*)d_in[12];
  const float* prelu_w = (const float*)d_in[13];

  char* ws = (char*)d_ws;
  bf16*  Y     = (bf16*)(ws);                      // 8192*2048*2   = 33554432 B
  bf16*  ADJB  = (bf16*)(ws + 33554432);           // 2*1024*1024*2 =  4194304 B
  float* HREAD = (float*)(ws + 37748736);          // 128*1024*4    =   524288 B
  float* WYT   = (float*)(ws + 38273024);          // 2*68*64*4     =    34816 B
  float* BY    = (float*)(ws + 38307840);          // 128*4         =      512 B
  float* HB    = (float*)(ws + 38308352);          // 64*4          =      256 B
  bf16*  W1B   = (bf16*)(ws + 38308608);           // 64*64*2       =     8192 B
  float* W2T   = (float*)(ws + 38316800);          // 64*64*4       =    16384 B

  float* out0 = (float*)d_out;           // read  [B,1,N]  = 131072 f32
  float* out2 = out0 + 131072;           // out2  [B,128,N] f32

  hipLaunchKernelGGL(k_prep_w,  dim3(67),         dim3(256), 0, stream,
                     W_in, b_in, W_gc, b_gc, W_out, b_out, WYT, BY, HB, W1B, W2T);
  hipLaunchKernelGGL(k_adj_bf16,dim3(2048),       dim3(256), 0, stream, adj, ADJB);
  hipLaunchKernelGGL(k_build_y, dim3(8, 3, 128),  dim3(256), 0, stream,
                     x, m, u, h, WYT, BY, HB, W2T, W_read, Y, out2, HREAD);
  hipLaunchKernelGGL(k_gemm,    dim3(64, 8),      dim3(256), 0, stream,
                     Y, ADJB, W1B, W_read, b_read, prelu_w, HREAD, out0, out2);
}

// Round 4
// 219.111 us; speedup vs baseline: 1.2294x; 1.0198x over previous
//
#include <hip/hip_runtime.h>
#include <hip/hip_bf16.h>
#include <stdint.h>

// Problem constants (SpatialDecoder: B=128, N=1024, DM=64, S=2, D_IN=68)
#define NB 128
#define NN 1024
#define NDM 64

typedef __bf16 bf16;
typedef __bf16 bf16x8_t __attribute__((ext_vector_type(8)));
typedef __bf16 bf16x4_t __attribute__((ext_vector_type(4)));
typedef __bf16 bf16x2_t __attribute__((ext_vector_type(2)));
typedef float f32x4 __attribute__((ext_vector_type(4)));

// ---------------------------------------------------------------------------
// k0: weight prep.
//  WyT[s][cp][o] = sum_c W_gc[o, s*64+c] * W_in[c, cp]   (transposed fold)
//  by[so]       = W_gc_s @ b_in
//  HB[o]        = b_out[o] + W_out[o,:64] . b_gc
//  W1B[o*64+c]  = bf16(W_out[o,c])          (gc half, for GEMM epilogue MFMA)
//  W2T[c*64+o]  = W_out[o,64+c]             (h half, transposed f32)
// ---------------------------------------------------------------------------
__global__ __launch_bounds__(256) void k_prep_w(
    const float* __restrict__ W_in, const float* __restrict__ b_in,
    const float* __restrict__ W_gc, const float* __restrict__ b_gc,
    const float* __restrict__ W_out, const float* __restrict__ b_out,
    float* __restrict__ WyT, float* __restrict__ by,
    float* __restrict__ HB, bf16* __restrict__ W1B, float* __restrict__ W2T) {
  int i = blockIdx.x * 256 + threadIdx.x;
  if (i < 8704) {  // WyT: [2][68][64]
    int o = i & 63, sc = i >> 6;
    int s = sc / 68, cp = sc % 68;
    float acc = 0.f;
    for (int c = 0; c < 64; ++c) acc += W_gc[o * 128 + s * 64 + c] * W_in[c * 68 + cp];
    WyT[i] = acc;
  } else if (i < 8832) {  // by: 128
    int so = i - 8704;
    int s = so >> 6, o = so & 63;
    float acc = 0.f;
    for (int c = 0; c < 64; ++c) acc += W_gc[o * 128 + s * 64 + c] * b_in[c];
    by[so] = acc;
  } else if (i < 8896) {  // HB: 64
    int o = i - 8832;
    float acc = b_out[o];
    for (int c = 0; c < 64; ++c) acc += W_out[o * 128 + c] * b_gc[c];
    HB[o] = acc;
  } else if (i < 12992) {  // W1B: 64x64 bf16
    int j = i - 8896;
    int o = j >> 6, c = j & 63;
    W1B[j] = (bf16)W_out[o * 128 + c];
  } else if (i < 17088) {  // W2T: [c][o] f32
    int j = i - 12992;
    int c = j >> 6, o = j & 63;
    W2T[j] = W_out[o * 128 + 64 + c];
  }
}

// ---------------------------------------------------------------------------
// k2: adj f32 -> bf16 (2M elements), float4-vectorized
// ---------------------------------------------------------------------------
__global__ __launch_bounds__(256) void k_adj_bf16(
    const float* __restrict__ adj, bf16* __restrict__ adjb) {
  int i = blockIdx.x * 256 + threadIdx.x;  // one float4 per thread
  float4 v = reinterpret_cast<const float4*>(adj)[i];
  bf16x4_t r;
  r.x = (bf16)v.x; r.y = (bf16)v.y; r.z = (bf16)v.z; r.w = (bf16)v.w;
  reinterpret_cast<bf16x4_t*>(adjb)[i] = r;
}

// ---------------------------------------------------------------------------
// k1: grid (N/128=8, 3, B).  LDS-staged via global_load_lds (width 16).
//  s<2 : Y[b, o, s, v] = by[so] + sum_{cp<68} WyT[s,cp,o] * X[cp,v]   (bf16)
//  s==2: hout[b,o,v] = HB[o] + sum_c W2T[c,o]*h[c,v]  -> out2[b, o, v] (f32)
//        + h passthrough + hread
// ---------------------------------------------------------------------------
__global__ __launch_bounds__(256) void k_build_y(
    const float* __restrict__ x, const float* __restrict__ m, const float* __restrict__ u,
    const float* __restrict__ h, const float* __restrict__ WyT, const float* __restrict__ by,
    const float* __restrict__ HB, const float* __restrict__ W2T,
    const float* __restrict__ W_read,
    bf16* __restrict__ Y, float* __restrict__ out2, float* __restrict__ hread) {
  __shared__ __align__(16) float Xs[68 * 128];   // 34816 B, row = channel
  __shared__ __align__(16) float Wt[68 * 64];    // 17408 B, Wt[cp][o]
  __shared__ float bl[64];
  __shared__ float Wrh[64];
  const int t = threadIdx.x;
  const int s = blockIdx.y, b = blockIdx.z;
  const int vb = blockIdx.x * 128;
  const bool hpath = (s == 2);

  if (!hpath) {
    for (int i = t; i < 68 * 64; i += 256) Wt[i] = WyT[s * 4352 + i];
    if (t < 64) bl[t] = by[s * 64 + t];
  } else {
    for (int i = t; i < 64 * 64; i += 256) Wt[i] = W2T[i];
    if (t < 64) { bl[t] = HB[t]; Wrh[t] = W_read[64 + t]; }
  }

  const int nch = hpath ? 2048 : 2176;
  for (int i = t; i < nch; i += 256) {
    int r = i >> 5, ck = i & 31;
    const float* src;
    if (!hpath) {
      if (r >= 4)      src = h + (size_t)(b * 64 + (r - 4)) * NN;
      else if (r == 0) src = x + (size_t)b * NN;
      else if (r == 1) src = m + (size_t)b * NN;
      else             src = u + (size_t)(b * 2 + (r - 2)) * NN;
    } else {
      src = h + (size_t)(b * 64 + r) * NN;
    }
    __builtin_amdgcn_global_load_lds((const uint32_t*)(src + vb + ck * 4),
                                     (uint32_t*)&Xs[i * 4], 16, 0, 0);
  }
  __syncthreads();

  const int og = t >> 6, lane = t & 63;
  const int v0 = lane * 2;

  float acc[16][2];
#pragma unroll
  for (int oi = 0; oi < 16; ++oi) {
    float bv = bl[og * 16 + oi];
    acc[oi][0] = bv; acc[oi][1] = bv;
  }

  const int NCH = hpath ? 64 : 68;
#pragma unroll 2
  for (int cp = 0; cp < NCH; ++cp) {
    float2 xv = *reinterpret_cast<const float2*>(&Xs[cp * 128 + v0]);
    const float4* wr = reinterpret_cast<const float4*>(&Wt[cp * 64 + og * 16]);
    float wv[16];
    *reinterpret_cast<float4*>(&wv[0])  = wr[0];
    *reinterpret_cast<float4*>(&wv[4])  = wr[1];
    *reinterpret_cast<float4*>(&wv[8])  = wr[2];
    *reinterpret_cast<float4*>(&wv[12]) = wr[3];
#pragma unroll
    for (int oi = 0; oi < 16; ++oi) {
      acc[oi][0] += wv[oi] * xv.x;
      acc[oi][1] += wv[oi] * xv.y;
    }
  }

  if (!hpath) {
#pragma unroll
    for (int oi = 0; oi < 16; ++oi) {
      bf16x2_t r;
      r.x = (bf16)acc[oi][0]; r.y = (bf16)acc[oi][1];
      size_t row = (size_t)(b * 64 + og * 16 + oi);
      *reinterpret_cast<bf16x2_t*>(&Y[row * 2048 + s * 1024 + vb + v0]) = r;
    }
  } else {
#pragma unroll
    for (int oi = 0; oi < 16; ++oi) {
      float2 st; st.x = acc[oi][0]; st.y = acc[oi][1];
      *reinterpret_cast<float2*>(&out2[(size_t)(b * 128 + og * 16 + oi) * NN + vb + v0]) = st;
    }
#pragma unroll
    for (int k = 0; k < 16; ++k) {
      int c = og * 16 + k;
      float2 hv = *reinterpret_cast<const float2*>(&Xs[c * 128 + v0]);
      *reinterpret_cast<float2*>(&out2[(size_t)(b * 128 + 64 + c) * NN + vb + v0]) = hv;
    }
    if (og == 0) {
      float hr0 = 0.f, hr1 = 0.f;
      for (int c = 0; c < 64; ++c) {
        float2 xv = *reinterpret_cast<const float2*>(&Xs[c * 128 + v0]);
        float wc = Wrh[c];
        hr0 += wc * xv.x; hr1 += wc * xv.y;
      }
      float2 st; st.x = hr0; st.y = hr1;
      *reinterpret_cast<float2*>(&hread[(size_t)b * NN + vb + v0]) = st;
    }
  }
}

// ---------------------------------------------------------------------------
// k3: fused GEMM + decoder epilogue.
// Main loop: BK=64, XOR-swizzled staging for conflict-free ds_read_b128.
//   LDS chunk c (16B) holds global k-quarter qg = (c&7) ^ (row&7), row = c>>3.
//   Fragment read: elem = r*64 + (((k2>>3)+q) ^ (r&7))*8  -> 2-way max (free).
// Phase 2: gc tile -> LDS bf16; per-wave MFMA out = W1 @ gc; add hout (out2),
// PReLU, write out2, reduce read output into out0.
// Grid: (64, 8).
// ---------------------------------------------------------------------------
__global__ __launch_bounds__(256) void k_gemm(
    const bf16* __restrict__ Y, const bf16* __restrict__ ADJB,
    const bf16* __restrict__ W1B, const float* __restrict__ W_read,
    const float* __restrict__ b_read, const float* __restrict__ prelu_w,
    const float* __restrict__ hread, float* __restrict__ out0, float* __restrict__ out2) {
  __shared__ __align__(16) union SMem {
    struct { bf16 As[128 * 64]; bf16 Bs[128 * 64]; } st;   // main loop staging (32 KB)
    bf16 gcs[2 * 128 * 72];                                // phase 2 gc tile (36 KB)
  } sm;
  __shared__ __align__(16) bf16 W1s[64 * 72];              // W1[o][c] padded (9 KB)
  __shared__ float Wrs[64];

  const int t = threadIdx.x;
  const int wave = t >> 6, lane = t & 63;
  const int rowA = blockIdx.x * 128;
  const int colB = blockIdx.y * 128;
  const int wm = (wave & 1) * 64, wn = (wave >> 1) * 64;
  const int fr = lane & 15;         // fragment row (m / n)
  const int q  = lane >> 4;         // k-quarter index within fragment

  for (int i = t; i < 4096; i += 256) W1s[(i >> 6) * 72 + (i & 63)] = W1B[i];
  if (t < 64) Wrs[t] = W_read[t];
  const float pw = prelu_w[0];
  const float br = b_read[0];

  f32x4 acc[4][4];
  const f32x4 zero = {0.f, 0.f, 0.f, 0.f};
#pragma unroll
  for (int i = 0; i < 4; ++i)
#pragma unroll
    for (int j = 0; j < 4; ++j) acc[i][j] = zero;

  // staging descriptors: 4 chunks each for A and B; c = t + 256*j
  int srow[4], sq[4];
#pragma unroll
  for (int j = 0; j < 4; ++j) {
    int c = t + 256 * j;
    srow[j] = c >> 3;
    sq[j] = (c & 7) ^ (srow[j] & 7);
  }
  __syncthreads();

  for (int k0 = 0; k0 < 2048; k0 += 64) {
    const int s = k0 >> 10, v0 = k0 & 1023;
    const bf16* bbase = ADJB + (size_t)s * (1024 * 1024) + v0;
#pragma unroll
    for (int j = 0; j < 4; ++j) {
      int c = t + 256 * j;
      __builtin_amdgcn_global_load_lds(
          (const uint32_t*)(Y + (size_t)(rowA + srow[j]) * 2048 + k0 + sq[j] * 8),
          (uint32_t*)&sm.st.As[c * 8], 16, 0, 0);
    }
#pragma unroll
    for (int j = 0; j < 4; ++j) {
      int c = t + 256 * j;
      __builtin_amdgcn_global_load_lds(
          (const uint32_t*)(bbase + (size_t)(colB + srow[j]) * 1024 + sq[j] * 8),
          (uint32_t*)&sm.st.Bs[c * 8], 16, 0, 0);
    }
    __syncthreads();
#pragma unroll
    for (int k2 = 0; k2 < 64; k2 += 32) {
      bf16x8_t af[4], bfr[4];
#pragma unroll
      for (int i = 0; i < 4; ++i) {
        const int r = wm + i * 16 + fr;
        af[i] = *reinterpret_cast<const bf16x8_t*>(
            &sm.st.As[r * 64 + ((((k2 >> 3) + q) ^ (r & 7)) << 3)]);
      }
#pragma unroll
      for (int i = 0; i < 4; ++i) {
        const int r = wn + i * 16 + fr;
        bfr[i] = *reinterpret_cast<const bf16x8_t*>(
            &sm.st.Bs[r * 64 + ((((k2 >> 3) + q) ^ (r & 7)) << 3)]);
      }
#pragma unroll
      for (int i = 0; i < 4; ++i)
#pragma unroll
        for (int j = 0; j < 4; ++j)
          acc[i][j] = __builtin_amdgcn_mfma_f32_16x16x32_bf16(af[i], bfr[j], acc[i][j], 0, 0, 0);
    }
    __syncthreads();
  }

  // ---- phase 2: gc tile -> LDS bf16, layout [b2][w_local][c] pad 72 ----
  {
    const int b2w = wm >> 6;
#pragma unroll
    for (int i = 0; i < 4; ++i) {
      const int cc0 = i * 16 + (lane >> 4) * 4;
#pragma unroll
      for (int j = 0; j < 4; ++j) {
        const int wl = wn + j * 16 + (lane & 15);
        bf16x4_t r;
        r.x = (bf16)acc[i][j][0]; r.y = (bf16)acc[i][j][1];
        r.z = (bf16)acc[i][j][2]; r.w = (bf16)acc[i][j][3];
        *reinterpret_cast<bf16x4_t*>(&sm.gcs[b2w * 9216 + wl * 72 + cc0]) = r;
      }
    }
  }
  __syncthreads();

  const int b2 = wave >> 1, jh = wave & 1;
  const int b = blockIdx.x * 2 + b2;
  const int fk = q * 8;

  f32x4 acc2[4][4];
#pragma unroll
  for (int i = 0; i < 4; ++i)
#pragma unroll
    for (int j = 0; j < 4; ++j) acc2[i][j] = zero;

#pragma unroll
  for (int k2 = 0; k2 < 64; k2 += 32) {
    bf16x8_t af2[4], bf2[4];
#pragma unroll
    for (int i = 0; i < 4; ++i)
      af2[i] = *reinterpret_cast<const bf16x8_t*>(&W1s[(i * 16 + fr) * 72 + k2 + fk]);
#pragma unroll
    for (int j = 0; j < 4; ++j)
      bf2[j] = *reinterpret_cast<const bf16x8_t*>(&sm.gcs[b2 * 9216 + (jh * 64 + j * 16 + fr) * 72 + k2 + fk]);
#pragma unroll
    for (int i = 0; i < 4; ++i)
#pragma unroll
      for (int j = 0; j < 4; ++j)
        acc2[i][j] = __builtin_amdgcn_mfma_f32_16x16x32_bf16(af2[i], bf2[j], acc2[i][j], 0, 0, 0);
  }

  float rd[4] = {0.f, 0.f, 0.f, 0.f};
#pragma unroll
  for (int i = 0; i < 4; ++i) {
    const int ob = i * 16 + (lane >> 4) * 4;
#pragma unroll
    for (int r = 0; r < 4; ++r) {
      const int o = ob + r;
      const float wr = Wrs[o];
#pragma unroll
      for (int j = 0; j < 4; ++j) {
        const int wg = colB + jh * 64 + j * 16 + (lane & 15);
        float* p = &out2[(size_t)(b * 128 + o) * 1024 + wg];
        float val = acc2[i][j][r] + *p;
        val = val >= 0.f ? val : pw * val;
        *p = val;
        rd[j] += wr * val;
      }
    }
  }
#pragma unroll
  for (int j = 0; j < 4; ++j) {
    rd[j] += __shfl_xor(rd[j], 16, 64);
    rd[j] += __shfl_xor(rd[j], 32, 64);
  }
  if (lane < 16) {
#pragma unroll
    for (int j = 0; j < 4; ++j) {
      const int wg = colB + jh * 64 + j * 16 + lane;
      out0[(size_t)b * 1024 + wg] = rd[j] + hread[(size_t)b * 1024 + wg] + br;
    }
  }
}

// ---------------------------------------------------------------------------
extern "C" void kernel_launch(void* const* d_in, const int* in_sizes, int n_in,
                              void* d_out, int out_size, void* d_ws, size_t ws_size,
                              hipStream_t stream) {
  (void)in_sizes; (void)n_in; (void)out_size; (void)ws_size;
  const float* x       = (const float*)d_in[0];
  const float* m       = (const float*)d_in[1];
  const float* u       = (const float*)d_in[2];
  const float* h       = (const float*)d_in[3];
  const float* adj     = (const float*)d_in[4];
  const float* W_in    = (const float*)d_in[5];
  const float* b_in    = (const float*)d_in[6];
  const float* W_gc    = (const float*)d_in[7];
  const float* b_gc    = (const float*)d_in[8];
  const float* W_out   = (const float*)d_in[9];
  const float* b_out   = (const float*)d_in[10];
  const float* W_read  = (const float*)d_in[11];
  const float* b_read  = (const float*)d_in[12];
  const float* prelu_w = (const float*)d_in[13];

  char* ws = (char*)d_ws;
  bf16*  Y     = (bf16*)(ws);                      // 8192*2048*2   = 33554432 B
  bf16*  ADJB  = (bf16*)(ws + 33554432);           // 2*1024*1024*2 =  4194304 B
  float* HREAD = (float*)(ws + 37748736);          // 128*1024*4    =   524288 B
  float* WYT   = (float*)(ws + 38273024);          // 2*68*64*4     =    34816 B
  float* BY    = (float*)(ws + 38307840);          // 128*4         =      512 B
  float* HB    = (float*)(ws + 38308352);          // 64*4          =      256 B
  bf16*  W1B   = (bf16*)(ws + 38308608);           // 64*64*2       =     8192 B
  float* W2T   = (float*)(ws + 38316800);          // 64*64*4       =    16384 B

  float* out0 = (float*)d_out;           // read  [B,1,N]  = 131072 f32
  float* out2 = out0 + 131072;           // out2  [B,128,N] f32

  hipLaunchKernelGGL(k_prep_w,  dim3(67),         dim3(256), 0, stream,
                     W_in, b_in, W_gc, b_gc, W_out, b_out, WYT, BY, HB, W1B, W2T);
  hipLaunchKernelGGL(k_adj_bf16,dim3(2048),       dim3(256), 0, stream, adj, ADJB);
  hipLaunchKernelGGL(k_build_y, dim3(8, 3, 128),  dim3(256), 0, stream,
                     x, m, u, h, WYT, BY, HB, W2T, W_read, Y, out2, HREAD);
  hipLaunchKernelGGL(k_gemm,    dim3(64, 8),      dim3(256), 0, stream,
                     Y, ADJB, W1B, W_read, b_read, prelu_w, HREAD, out0, out2);
}

// Round 5
// 200.964 us; speedup vs baseline: 1.3404x; 1.0903x over previous
//
#include <hip/hip_runtime.h>
#include <hip/hip_bf16.h>
#include <stdint.h>

// Problem constants (SpatialDecoder: B=128, N=1024, DM=64, S=2, D_IN=68)
#define NB 128
#define NN 1024
#define NDM 64

typedef __bf16 bf16;
typedef __bf16 bf16x8_t __attribute__((ext_vector_type(8)));
typedef __bf16 bf16x4_t __attribute__((ext_vector_type(4)));
typedef __bf16 bf16x2_t __attribute__((ext_vector_type(2)));
typedef float f32x4 __attribute__((ext_vector_type(4)));

// ---------------------------------------------------------------------------
// k0: weight prep for the MFMA build_y + GEMM epilogue.
//  WAT [208][64] bf16, pre-XOR-swizzled: WAT[r][cq*8+j] = WA[r][(cq^(r&7))*8+j]
//    WA rows: 0..127  = Wy[s,o][4+c]   (folded W_gc@W_in, h-channel part)
//             128..191= W_out[o][64+c] (hout)
//             192     = W_read[64+c]   (hread)   193..207 = 0
//  WYX [128][4] f32 : Wy[s,o][0..3]  (x,m,u rank-4 part)
//  BIAS[208]  f32 : rows 0..127 = W_gc_s@b_in ; 128..191 = b_out + W1.b_gc ; 0
//  W1B [64][64] bf16 : W_out[o][c] gc-half (for k_gemm epilogue MFMA)
// ---------------------------------------------------------------------------
__global__ __launch_bounds__(256) void k_prep_w(
    const float* __restrict__ W_in, const float* __restrict__ b_in,
    const float* __restrict__ W_gc, const float* __restrict__ b_gc,
    const float* __restrict__ W_out, const float* __restrict__ b_out,
    const float* __restrict__ W_read,
    bf16* __restrict__ WAT, float* __restrict__ WYX, float* __restrict__ BIAS,
    bf16* __restrict__ W1B) {
  int i = blockIdx.x * 256 + threadIdx.x;
  if (i < 13312) {  // WAT
    int r = i >> 6, cc = i & 63;
    int cq = cc >> 3, j = cc & 7;
    int c = ((cq ^ (r & 7)) << 3) + j;   // source h-channel 0..63
    float val;
    if (r < 128) {
      int s = r >> 6, o = r & 63;
      val = 0.f;
      for (int k = 0; k < 64; ++k) val += W_gc[o * 128 + s * 64 + k] * W_in[k * 68 + 4 + c];
    } else if (r < 192) {
      val = W_out[(r - 128) * 128 + 64 + c];
    } else if (r == 192) {
      val = W_read[64 + c];
    } else {
      val = 0.f;
    }
    WAT[i] = (bf16)val;
  } else if (i < 13824) {  // WYX
    int idx = i - 13312;
    int r = idx >> 2, j = idx & 3;
    int s = r >> 6, o = r & 63;
    float val = 0.f;
    for (int k = 0; k < 64; ++k) val += W_gc[o * 128 + s * 64 + k] * W_in[k * 68 + j];
    WYX[idx] = val;
  } else if (i < 14032) {  // BIAS[208]
    int r = i - 13824;
    float val = 0.f;
    if (r < 128) {
      int s = r >> 6, o = r & 63;
      for (int k = 0; k < 64; ++k) val += W_gc[o * 128 + s * 64 + k] * b_in[k];
    } else if (r < 192) {
      int o = r - 128;
      val = b_out[o];
      for (int k = 0; k < 64; ++k) val += W_out[o * 128 + k] * b_gc[k];
    }
    BIAS[r] = val;
  } else if (i < 18128) {  // W1B
    int j = i - 14032;
    int o = j >> 6, c = j & 63;
    W1B[j] = (bf16)W_out[o * 128 + c];
  }
}

// ---------------------------------------------------------------------------
// k2: adj f32 -> bf16 (2M elements), float4-vectorized
// ---------------------------------------------------------------------------
__global__ __launch_bounds__(256) void k_adj_bf16(
    const float* __restrict__ adj, bf16* __restrict__ adjb) {
  int i = blockIdx.x * 256 + threadIdx.x;  // one float4 per thread
  float4 v = reinterpret_cast<const float4*>(adj)[i];
  bf16x4_t r;
  r.x = (bf16)v.x; r.y = (bf16)v.y; r.z = (bf16)v.z; r.w = (bf16)v.w;
  reinterpret_cast<bf16x4_t*>(adjb)[i] = r;
}

// ---------------------------------------------------------------------------
// k_ht: h [b][c][v] f32 -> HT [b][v][64] bf16, pre-XOR-swizzled:
//   HT[b*1024+v][cq*8+j] = bf16( h[b][ (cq^(v&7))*8 + j ][v] )
// + h passthrough: out2[b][64+c][v] = h[b][c][v] (exact f32)
// Grid (8, 128): v-tile 128 per block.
// ---------------------------------------------------------------------------
__global__ __launch_bounds__(256) void k_ht(
    const float* __restrict__ h, bf16* __restrict__ HT, float* __restrict__ out2) {
  __shared__ __align__(16) float T[64 * 128];   // 32 KB, row = channel (no pad)
  const int t = threadIdx.x;
  const int vb = blockIdx.x * 128;
  const int b = blockIdx.y;
  for (int i = t; i < 2048; i += 256) {
    int r = i >> 5, ck = i & 31;
    float4 v4 = *reinterpret_cast<const float4*>(&h[(size_t)(b * 64 + r) * NN + vb + ck * 4]);
    *reinterpret_cast<float4*>(&T[r * 128 + ck * 4]) = v4;
    *reinterpret_cast<float4*>(&out2[(size_t)(b * 128 + 64 + r) * NN + vb + ck * 4]) = v4;
  }
  __syncthreads();
  const int v = t >> 1, half = t & 1;
#pragma unroll
  for (int cc = 0; cc < 4; ++cc) {
    int cq = half * 4 + cc;
    int cbase = (cq ^ (v & 7)) << 3;
    bf16x8_t pk;
#pragma unroll
    for (int j = 0; j < 8; ++j) pk[j] = (bf16)T[(cbase + j) * 128 + v];
    *reinterpret_cast<bf16x8_t*>(&HT[((size_t)b * NN + vb + v) * 64 + cq * 8]) = pk;
  }
}

// ---------------------------------------------------------------------------
// k1 (build_y v3, MFMA): per (v-tile 128, b):
//   D[v][r] = BIAS[r] + WYX[r]*X4[v] (C-init, rank-4 x/m/u)
//           + sum_{c<64} h_bf16[c][v] * WA[r][c]     (2x mfma 16x16x32, K=64)
//   rows r: 0..127 -> Y[b*64+(r&63)][ (r>>6)*1024 + v ]  bf16
//           128..191 -> out2[b][r-128][v]  f32 (hout, pre-PReLU)
//           192      -> hread[b][v]
// A-operand = HT tile (m=v), B-operand = WAT (n=r); both pre-swizzled, staged
// via linear global_load_lds; fragment reads are 2-way max (free).
// Grid (8, 128), 256 thr; wave owns v-tiles {w, w+4}, loops 13 n-tiles.
// ---------------------------------------------------------------------------
__global__ __launch_bounds__(256) void k_build_y(
    const float* __restrict__ x, const float* __restrict__ m, const float* __restrict__ u,
    const bf16* __restrict__ HT, const bf16* __restrict__ WAT,
    const float* __restrict__ WYX, const float* __restrict__ BIAS,
    bf16* __restrict__ Y, float* __restrict__ out2, float* __restrict__ hread) {
  __shared__ __align__(16) bf16 HTs[128 * 64];    // 16384 B
  __shared__ __align__(16) bf16 WAs[208 * 64];    // 26624 B
  __shared__ __align__(16) float X4L[128 * 4];    // 2048 B
  __shared__ __align__(16) float WYXs[128 * 4];   // 2048 B
  __shared__ __align__(16) float biasL[208];      // 832 B
  const int t = threadIdx.x;
  const int vb = blockIdx.x * 128;
  const int b = blockIdx.y;

  {
    const bf16* src = HT + ((size_t)b * NN + vb) * 64;
    for (int i = t; i < 1024; i += 256)
      __builtin_amdgcn_global_load_lds((const uint32_t*)(src + i * 8), (uint32_t*)&HTs[i * 8], 16, 0, 0);
    for (int i = t; i < 1664; i += 256)
      __builtin_amdgcn_global_load_lds((const uint32_t*)(WAT + i * 8), (uint32_t*)&WAs[i * 8], 16, 0, 0);
    if (t < 128)
      __builtin_amdgcn_global_load_lds((const uint32_t*)(WYX + t * 4), (uint32_t*)&WYXs[t * 4], 16, 0, 0);
    if (t < 52)
      __builtin_amdgcn_global_load_lds((const uint32_t*)(BIAS + t * 4), (uint32_t*)&biasL[t * 4], 16, 0, 0);
    if (t < 128) {
      int v = t;
      float4 x4;
      x4.x = x[(size_t)b * NN + vb + v];
      x4.y = m[(size_t)b * NN + vb + v];
      x4.z = u[(size_t)(b * 2) * NN + vb + v];
      x4.w = u[(size_t)(b * 2 + 1) * NN + vb + v];
      *reinterpret_cast<float4*>(&X4L[v * 4]) = x4;
    }
  }
  __syncthreads();

  const int wave = t >> 6, lane = t & 63;
  const int q = lane >> 4, lx = lane & 7, o16 = lane & 15;

#pragma unroll
  for (int vi = 0; vi < 2; ++vi) {
    const int vt = wave + vi * 4;
    const int vrow = vt * 16 + o16;
    bf16x8_t af0 = *reinterpret_cast<const bf16x8_t*>(&HTs[vrow * 64 + ((q ^ lx) << 3)]);
    bf16x8_t af1 = *reinterpret_cast<const bf16x8_t*>(&HTs[vrow * 64 + (((q + 4) ^ lx) << 3)]);
    float4 x4r[4];
#pragma unroll
    for (int r = 0; r < 4; ++r)
      x4r[r] = *reinterpret_cast<const float4*>(&X4L[(vt * 16 + q * 4 + r) * 4]);
    const int vg = vb + vt * 16 + q * 4;
    for (int nt = 0; nt < 13; ++nt) {
      const int rr = nt * 16 + o16;
      bf16x8_t bf0 = *reinterpret_cast<const bf16x8_t*>(&WAs[rr * 64 + ((q ^ lx) << 3)]);
      bf16x8_t bf1 = *reinterpret_cast<const bf16x8_t*>(&WAs[rr * 64 + (((q + 4) ^ lx) << 3)]);
      float bsv = biasL[rr];
      f32x4 c0 = {bsv, bsv, bsv, bsv};
      if (nt < 8) {
        float4 wy = *reinterpret_cast<const float4*>(&WYXs[rr * 4]);
#pragma unroll
        for (int r = 0; r < 4; ++r)
          c0[r] += wy.x * x4r[r].x + wy.y * x4r[r].y + wy.z * x4r[r].z + wy.w * x4r[r].w;
      }
      f32x4 acc = __builtin_amdgcn_mfma_f32_16x16x32_bf16(af0, bf0, c0, 0, 0, 0);
      acc = __builtin_amdgcn_mfma_f32_16x16x32_bf16(af1, bf1, acc, 0, 0, 0);
      if (nt < 8) {
        const int s = nt >> 2;
        const int o = rr - s * 64;
        bf16x4_t pk;
        pk.x = (bf16)acc[0]; pk.y = (bf16)acc[1]; pk.z = (bf16)acc[2]; pk.w = (bf16)acc[3];
        *reinterpret_cast<bf16x4_t*>(&Y[(size_t)(b * 64 + o) * 2048 + s * 1024 + vg]) = pk;
      } else if (nt < 12) {
        const int o = rr - 128;
        float4 st; st.x = acc[0]; st.y = acc[1]; st.z = acc[2]; st.w = acc[3];
        *reinterpret_cast<float4*>(&out2[(size_t)(b * 128 + o) * NN + vg]) = st;
      } else if (o16 == 0) {
        float4 st; st.x = acc[0]; st.y = acc[1]; st.z = acc[2]; st.w = acc[3];
        *reinterpret_cast<float4*>(&hread[(size_t)b * NN + vg]) = st;
      }
    }
  }
}

// ---------------------------------------------------------------------------
// k3: fused GEMM + decoder epilogue (unchanged from round 4).
// ---------------------------------------------------------------------------
__global__ __launch_bounds__(256) void k_gemm(
    const bf16* __restrict__ Y, const bf16* __restrict__ ADJB,
    const bf16* __restrict__ W1B, const float* __restrict__ W_read,
    const float* __restrict__ b_read, const float* __restrict__ prelu_w,
    const float* __restrict__ hread, float* __restrict__ out0, float* __restrict__ out2) {
  __shared__ __align__(16) union SMem {
    struct { bf16 As[128 * 64]; bf16 Bs[128 * 64]; } st;   // main loop staging (32 KB)
    bf16 gcs[2 * 128 * 72];                                // phase 2 gc tile (36 KB)
  } sm;
  __shared__ __align__(16) bf16 W1s[64 * 72];              // W1[o][c] padded (9 KB)
  __shared__ float Wrs[64];

  const int t = threadIdx.x;
  const int wave = t >> 6, lane = t & 63;
  const int rowA = blockIdx.x * 128;
  const int colB = blockIdx.y * 128;
  const int wm = (wave & 1) * 64, wn = (wave >> 1) * 64;
  const int fr = lane & 15;         // fragment row (m / n)
  const int q  = lane >> 4;         // k-quarter index within fragment

  for (int i = t; i < 4096; i += 256) W1s[(i >> 6) * 72 + (i & 63)] = W1B[i];
  if (t < 64) Wrs[t] = W_read[t];
  const float pw = prelu_w[0];
  const float br = b_read[0];

  f32x4 acc[4][4];
  const f32x4 zero = {0.f, 0.f, 0.f, 0.f};
#pragma unroll
  for (int i = 0; i < 4; ++i)
#pragma unroll
    for (int j = 0; j < 4; ++j) acc[i][j] = zero;

  int srow[4], sq[4];
#pragma unroll
  for (int j = 0; j < 4; ++j) {
    int c = t + 256 * j;
    srow[j] = c >> 3;
    sq[j] = (c & 7) ^ (srow[j] & 7);
  }
  __syncthreads();

  for (int k0 = 0; k0 < 2048; k0 += 64) {
    const int s = k0 >> 10, v0 = k0 & 1023;
    const bf16* bbase = ADJB + (size_t)s * (1024 * 1024) + v0;
#pragma unroll
    for (int j = 0; j < 4; ++j) {
      int c = t + 256 * j;
      __builtin_amdgcn_global_load_lds(
          (const uint32_t*)(Y + (size_t)(rowA + srow[j]) * 2048 + k0 + sq[j] * 8),
          (uint32_t*)&sm.st.As[c * 8], 16, 0, 0);
    }
#pragma unroll
    for (int j = 0; j < 4; ++j) {
      int c = t + 256 * j;
      __builtin_amdgcn_global_load_lds(
          (const uint32_t*)(bbase + (size_t)(colB + srow[j]) * 1024 + sq[j] * 8),
          (uint32_t*)&sm.st.Bs[c * 8], 16, 0, 0);
    }
    __syncthreads();
#pragma unroll
    for (int k2 = 0; k2 < 64; k2 += 32) {
      bf16x8_t af[4], bfr[4];
#pragma unroll
      for (int i = 0; i < 4; ++i) {
        const int r = wm + i * 16 + fr;
        af[i] = *reinterpret_cast<const bf16x8_t*>(
            &sm.st.As[r * 64 + ((((k2 >> 3) + q) ^ (r & 7)) << 3)]);
      }
#pragma unroll
      for (int i = 0; i < 4; ++i) {
        const int r = wn + i * 16 + fr;
        bfr[i] = *reinterpret_cast<const bf16x8_t*>(
            &sm.st.Bs[r * 64 + ((((k2 >> 3) + q) ^ (r & 7)) << 3)]);
      }
#pragma unroll
      for (int i = 0; i < 4; ++i)
#pragma unroll
        for (int j = 0; j < 4; ++j)
          acc[i][j] = __builtin_amdgcn_mfma_f32_16x16x32_bf16(af[i], bfr[j], acc[i][j], 0, 0, 0);
    }
    __syncthreads();
  }

  {
    const int b2w = wm >> 6;
#pragma unroll
    for (int i = 0; i < 4; ++i) {
      const int cc0 = i * 16 + (lane >> 4) * 4;
#pragma unroll
      for (int j = 0; j < 4; ++j) {
        const int wl = wn + j * 16 + (lane & 15);
        bf16x4_t r;
        r.x = (bf16)acc[i][j][0]; r.y = (bf16)acc[i][j][1];
        r.z = (bf16)acc[i][j][2]; r.w = (bf16)acc[i][j][3];
        *reinterpret_cast<bf16x4_t*>(&sm.gcs[b2w * 9216 + wl * 72 + cc0]) = r;
      }
    }
  }
  __syncthreads();

  const int b2 = wave >> 1, jh = wave & 1;
  const int b = blockIdx.x * 2 + b2;
  const int fk = q * 8;

  f32x4 acc2[4][4];
#pragma unroll
  for (int i = 0; i < 4; ++i)
#pragma unroll
    for (int j = 0; j < 4; ++j) acc2[i][j] = zero;

#pragma unroll
  for (int k2 = 0; k2 < 64; k2 += 32) {
    bf16x8_t af2[4], bf2[4];
#pragma unroll
    for (int i = 0; i < 4; ++i)
      af2[i] = *reinterpret_cast<const bf16x8_t*>(&W1s[(i * 16 + fr) * 72 + k2 + fk]);
#pragma unroll
    for (int j = 0; j < 4; ++j)
      bf2[j] = *reinterpret_cast<const bf16x8_t*>(&sm.gcs[b2 * 9216 + (jh * 64 + j * 16 + fr) * 72 + k2 + fk]);
#pragma unroll
    for (int i = 0; i < 4; ++i)
#pragma unroll
      for (int j = 0; j < 4; ++j)
        acc2[i][j] = __builtin_amdgcn_mfma_f32_16x16x32_bf16(af2[i], bf2[j], acc2[i][j], 0, 0, 0);
  }

  float rd[4] = {0.f, 0.f, 0.f, 0.f};
#pragma unroll
  for (int i = 0; i < 4; ++i) {
    const int ob = i * 16 + (lane >> 4) * 4;
#pragma unroll
    for (int r = 0; r < 4; ++r) {
      const int o = ob + r;
      const float wr = Wrs[o];
#pragma unroll
      for (int j = 0; j < 4; ++j) {
        const int wg = colB + jh * 64 + j * 16 + (lane & 15);
        float* p = &out2[(size_t)(b * 128 + o) * 1024 + wg];
        float val = acc2[i][j][r] + *p;
        val = val >= 0.f ? val : pw * val;
        *p = val;
        rd[j] += wr * val;
      }
    }
  }
#pragma unroll
  for (int j = 0; j < 4; ++j) {
    rd[j] += __shfl_xor(rd[j], 16, 64);
    rd[j] += __shfl_xor(rd[j], 32, 64);
  }
  if (lane < 16) {
#pragma unroll
    for (int j = 0; j < 4; ++j) {
      const int wg = colB + jh * 64 + j * 16 + lane;
      out0[(size_t)b * 1024 + wg] = rd[j] + hread[(size_t)b * 1024 + wg] + br;
    }
  }
}

// ---------------------------------------------------------------------------
extern "C" void kernel_launch(void* const* d_in, const int* in_sizes, int n_in,
                              void* d_out, int out_size, void* d_ws, size_t ws_size,
                              hipStream_t stream) {
  (void)in_sizes; (void)n_in; (void)out_size; (void)ws_size;
  const float* x       = (const float*)d_in[0];
  const float* m       = (const float*)d_in[1];
  const float* u       = (const float*)d_in[2];
  const float* h       = (const float*)d_in[3];
  const float* adj     = (const float*)d_in[4];
  const float* W_in    = (const float*)d_in[5];
  const float* b_in    = (const float*)d_in[6];
  const float* W_gc    = (const float*)d_in[7];
  const float* b_gc    = (const float*)d_in[8];
  const float* W_out   = (const float*)d_in[9];
  const float* b_out   = (const float*)d_in[10];
  const float* W_read  = (const float*)d_in[11];
  const float* b_read  = (const float*)d_in[12];
  const float* prelu_w = (const float*)d_in[13];

  char* ws = (char*)d_ws;
  bf16*  Y     = (bf16*)(ws);                      // 33554432 B
  bf16*  ADJB  = (bf16*)(ws + 33554432);           //  4194304 B -> 37748736
  bf16*  HT    = (bf16*)(ws + 37748736);           // 16777216 B -> 54525952
  float* HREAD = (float*)(ws + 54525952);          //   524288 B -> 55050240
  bf16*  WAT   = (bf16*)(ws + 55050240);           //    26624 B -> 55076864
  float* WYX   = (float*)(ws + 55076864);          //     2048 B -> 55078912
  float* BIAS  = (float*)(ws + 55078912);          //      832 B (pad to 1024) -> 55079936
  bf16*  W1B   = (bf16*)(ws + 55079936);           //     8192 B -> 55088128

  float* out0 = (float*)d_out;           // read  [B,1,N]  = 131072 f32
  float* out2 = out0 + 131072;           // out2  [B,128,N] f32

  hipLaunchKernelGGL(k_prep_w,  dim3(71),        dim3(256), 0, stream,
                     W_in, b_in, W_gc, b_gc, W_out, b_out, W_read, WAT, WYX, BIAS, W1B);
  hipLaunchKernelGGL(k_adj_bf16,dim3(2048),      dim3(256), 0, stream, adj, ADJB);
  hipLaunchKernelGGL(k_ht,      dim3(8, 128),    dim3(256), 0, stream, h, HT, out2);
  hipLaunchKernelGGL(k_build_y, dim3(8, 128),    dim3(256), 0, stream,
                     x, m, u, HT, WAT, WYX, BIAS, Y, out2, HREAD);
  hipLaunchKernelGGL(k_gemm,    dim3(64, 8),     dim3(256), 0, stream,
                     Y, ADJB, W1B, W_read, b_read, prelu_w, HREAD, out0, out2);
}

// Round 6
// 183.928 us; speedup vs baseline: 1.4645x; 1.0926x over previous
//
#include <hip/hip_runtime.h>
#include <hip/hip_bf16.h>
#include <stdint.h>

// Problem constants (SpatialDecoder: B=128, N=1024, DM=64, S=2, D_IN=68)
#define NB 128
#define NN 1024
#define NDM 64

typedef __bf16 bf16;
typedef __bf16 bf16x8_t __attribute__((ext_vector_type(8)));
typedef __bf16 bf16x4_t __attribute__((ext_vector_type(4)));
typedef float f32x4 __attribute__((ext_vector_type(4)));

// ---------------------------------------------------------------------------
// k_prep: adj f32->bf16 cast (blocks < 2048) + weight prep (blocks >= 2048).
//  WAT [128][64] bf16 swizzled: WAT[r][cq*8+j] = Wy_h[r][((cq^(r&7))<<3)+j]
//      Wy_h[r=s*64+o][c] = sum_k W_gc[o,s*64+k] * W_in[k, 4+c]
//  WYX [128][4] f32 : folded x/m/u rank-4 weights
//  BIAS[128] f32 : W_gc_s @ b_in   (Y bias)
//  W1B [64][64] bf16 : W_out[o][c]      (gc half)
//  A2B [80][64] bf16 : rows 0..63 W_out[o][64+c]; row 64 W_read[64+c]; 65.. 0
//  HBv [64] f32 : b_out[o] + W_out[o,:64].b_gc
// ---------------------------------------------------------------------------
__global__ __launch_bounds__(256) void k_prep(
    const float* __restrict__ adj,
    const float* __restrict__ W_in, const float* __restrict__ b_in,
    const float* __restrict__ W_gc, const float* __restrict__ b_gc,
    const float* __restrict__ W_out, const float* __restrict__ b_out,
    const float* __restrict__ W_read,
    bf16* __restrict__ adjb, bf16* __restrict__ WAT, float* __restrict__ WYX,
    float* __restrict__ BIAS, bf16* __restrict__ W1B, bf16* __restrict__ A2B,
    float* __restrict__ HBv) {
  const int bx = blockIdx.x;
  if (bx < 2048) {
    int i = bx * 256 + threadIdx.x;  // one float4 per thread
    float4 v = reinterpret_cast<const float4*>(adj)[i];
    bf16x4_t r;
    r.x = (bf16)v.x; r.y = (bf16)v.y; r.z = (bf16)v.z; r.w = (bf16)v.w;
    reinterpret_cast<bf16x4_t*>(adjb)[i] = r;
    return;
  }
  int i = (bx - 2048) * 256 + threadIdx.x;
  if (i < 8192) {  // WAT
    int r = i >> 6, cc = i & 63;
    int cq = cc >> 3, j = cc & 7;
    int c = ((cq ^ (r & 7)) << 3) + j;
    int s = r >> 6, o = r & 63;
    float val = 0.f;
    for (int k = 0; k < 64; ++k) val += W_gc[o * 128 + s * 64 + k] * W_in[k * 68 + 4 + c];
    WAT[i] = (bf16)val;
  } else if (i < 8704) {  // WYX
    int idx = i - 8192;
    int r = idx >> 2, jj = idx & 3;
    int s = r >> 6, o = r & 63;
    float val = 0.f;
    for (int k = 0; k < 64; ++k) val += W_gc[o * 128 + s * 64 + k] * W_in[k * 68 + jj];
    WYX[idx] = val;
  } else if (i < 8832) {  // BIAS
    int r = i - 8704;
    int s = r >> 6, o = r & 63;
    float val = 0.f;
    for (int k = 0; k < 64; ++k) val += W_gc[o * 128 + s * 64 + k] * b_in[k];
    BIAS[r] = val;
  } else if (i < 12928) {  // W1B
    int j = i - 8832;
    int o = j >> 6, c = j & 63;
    W1B[j] = (bf16)W_out[o * 128 + c];
  } else if (i < 18048) {  // A2B (80x64)
    int j = i - 12928;
    int r = j >> 6, c = j & 63;
    float val = 0.f;
    if (r < 64) val = W_out[r * 128 + 64 + c];
    else if (r == 64) val = W_read[64 + c];
    A2B[j] = (bf16)val;
  } else if (i < 18112) {  // HBv
    int o = i - 18048;
    float val = b_out[o];
    for (int c = 0; c < 64; ++c) val += W_out[o * 128 + c] * b_gc[c];
    HBv[o] = val;
  }
}

// ---------------------------------------------------------------------------
// k_build (fused transpose + Y build). Grid (8, 128), 256 thr.
//  1) stage h tile [64c x 128v] f32 -> LDS T via global_load_lds
//  2) transpose/pack -> HTs [128v][64c] bf16, XOR-swizzled (cq = kq^(v&7));
//     write same to global HT (for k_gemm phase-3) + h passthrough to out2
//  3) MFMA: Y[b, so, v] = BIAS[so] + WYX[so].x4[v] + sum_c h[c][v]*Wy_h[so][c]
// ---------------------------------------------------------------------------
__global__ __launch_bounds__(256) void k_build(
    const float* __restrict__ x, const float* __restrict__ m, const float* __restrict__ u,
    const float* __restrict__ h, const bf16* __restrict__ WAT,
    const float* __restrict__ WYX, const float* __restrict__ BIAS,
    bf16* __restrict__ Y, bf16* __restrict__ HT, float* __restrict__ out2) {
  __shared__ __align__(16) float T[64 * 128];     // 32 KB
  __shared__ __align__(16) bf16 HTs[128 * 64];    // 16 KB
  __shared__ __align__(16) bf16 WAs[128 * 64];    // 16 KB
  __shared__ __align__(16) float X4L[128 * 4];    // 2 KB
  __shared__ __align__(16) float WYXs[128 * 4];   // 2 KB
  __shared__ __align__(16) float biasL[128];
  const int t = threadIdx.x;
  const int vb = blockIdx.x * 128;
  const int b = blockIdx.y;

  for (int i = t; i < 2048; i += 256)
    __builtin_amdgcn_global_load_lds(
        (const uint32_t*)(h + (size_t)(b * 64 + (i >> 5)) * NN + vb + (i & 31) * 4),
        (uint32_t*)&T[i * 4], 16, 0, 0);
  for (int i = t; i < 1024; i += 256)
    __builtin_amdgcn_global_load_lds((const uint32_t*)(WAT + i * 8), (uint32_t*)&WAs[i * 8], 16, 0, 0);
  if (t < 128)
    __builtin_amdgcn_global_load_lds((const uint32_t*)(WYX + t * 4), (uint32_t*)&WYXs[t * 4], 16, 0, 0);
  if (t < 32)
    __builtin_amdgcn_global_load_lds((const uint32_t*)(BIAS + t * 4), (uint32_t*)&biasL[t * 4], 16, 0, 0);
  if (t < 128) {
    float4 x4;
    x4.x = x[(size_t)b * NN + vb + t];
    x4.y = m[(size_t)b * NN + vb + t];
    x4.z = u[(size_t)(b * 2) * NN + vb + t];
    x4.w = u[(size_t)(b * 2 + 1) * NN + vb + t];
    *reinterpret_cast<float4*>(&X4L[t * 4]) = x4;
  }
  __syncthreads();

  // transpose/pack: thread pair covers one v
  {
    const int v = t >> 1, half = t & 1;
#pragma unroll
    for (int cc = 0; cc < 4; ++cc) {
      int cq = half * 4 + cc;
      int cbase = (cq ^ (v & 7)) << 3;
      bf16x8_t pk;
#pragma unroll
      for (int j = 0; j < 8; ++j) pk[j] = (bf16)T[(cbase + j) * 128 + v];
      *reinterpret_cast<bf16x8_t*>(&HTs[v * 64 + cq * 8]) = pk;
      *reinterpret_cast<bf16x8_t*>(&HT[((size_t)(b << 10) + vb + v) * 64 + cq * 8]) = pk;
    }
  }
  // h passthrough (exact f32)
  for (int i = t; i < 2048; i += 256) {
    int r = i >> 5, ck = i & 31;
    float4 hv = *reinterpret_cast<const float4*>(&T[r * 128 + ck * 4]);
    *reinterpret_cast<float4*>(&out2[(size_t)(b * 128 + 64 + r) * NN + vb + ck * 4]) = hv;
  }
  __syncthreads();

  const int wave = t >> 6, lane = t & 63;
  const int q = lane >> 4, lx = lane & 7, o16 = lane & 15;
  const int offK0 = (q ^ lx) << 3, offK1 = ((q + 4) ^ lx) << 3;

#pragma unroll
  for (int vi = 0; vi < 2; ++vi) {
    const int vt = wave + vi * 4;
    const int vrow = vt * 16 + o16;
    bf16x8_t af0 = *reinterpret_cast<const bf16x8_t*>(&HTs[vrow * 64 + offK0]);
    bf16x8_t af1 = *reinterpret_cast<const bf16x8_t*>(&HTs[vrow * 64 + offK1]);
    float4 x4r[4];
#pragma unroll
    for (int r = 0; r < 4; ++r)
      x4r[r] = *reinterpret_cast<const float4*>(&X4L[(vt * 16 + q * 4 + r) * 4]);
    const int vg = vb + vt * 16 + q * 4;
    for (int nt = 0; nt < 8; ++nt) {
      const int rr = nt * 16 + o16;
      bf16x8_t bf0 = *reinterpret_cast<const bf16x8_t*>(&WAs[rr * 64 + offK0]);
      bf16x8_t bf1 = *reinterpret_cast<const bf16x8_t*>(&WAs[rr * 64 + offK1]);
      float bsv = biasL[rr];
      float4 wy = *reinterpret_cast<const float4*>(&WYXs[rr * 4]);
      f32x4 c0;
#pragma unroll
      for (int r = 0; r < 4; ++r)
        c0[r] = bsv + wy.x * x4r[r].x + wy.y * x4r[r].y + wy.z * x4r[r].z + wy.w * x4r[r].w;
      f32x4 acc = __builtin_amdgcn_mfma_f32_16x16x32_bf16(af0, bf0, c0, 0, 0, 0);
      acc = __builtin_amdgcn_mfma_f32_16x16x32_bf16(af1, bf1, acc, 0, 0, 0);
      const int s = nt >> 2;
      const int o = rr - s * 64;
      bf16x4_t pk;
      pk.x = (bf16)acc[0]; pk.y = (bf16)acc[1]; pk.z = (bf16)acc[2]; pk.w = (bf16)acc[3];
      *reinterpret_cast<bf16x4_t*>(&Y[(size_t)(b * 64 + o) * 2048 + s * 1024 + vg]) = pk;
    }
  }
}

// ---------------------------------------------------------------------------
// k_gemm: main GEMM (BK=64, XOR swizzle, loop-carried staging pointers)
// + full decoder epilogue:
//   phase2: out[o,w] += W1 @ gc      (B = gcs LDS, from accs)
//   phase3: out[o,w] += [W2;Wr] @ h  (B-frags direct from swizzled HT global)
//   C-init = HB[o]; then PReLU -> out2[b,0..63]; rd-reduce + hread -> out0.
// Grid (64, 8).
// ---------------------------------------------------------------------------
__global__ __launch_bounds__(256) void k_gemm(
    const bf16* __restrict__ Y, const bf16* __restrict__ ADJB,
    const bf16* __restrict__ HT,
    const bf16* __restrict__ W1B, const bf16* __restrict__ A2B,
    const float* __restrict__ HBv, const float* __restrict__ W_read,
    const float* __restrict__ b_read, const float* __restrict__ prelu_w,
    float* __restrict__ out0, float* __restrict__ out2) {
  __shared__ __align__(16) union SMem {
    struct { bf16 As[128 * 64]; bf16 Bs[128 * 64]; } st;   // 32 KB staging
    bf16 gcs[2 * 128 * 72];                                // 36.9 KB phase-2
  } sm;
  __shared__ __align__(16) bf16 W1s[64 * 72];              // 9.2 KB
  __shared__ __align__(16) bf16 A2s[80 * 72];              // 11.5 KB
  __shared__ float HBs[64];
  __shared__ float Wrs[64];

  const int t = threadIdx.x;
  const int wave = t >> 6, lane = t & 63;
  const int rowA = blockIdx.x * 128;
  const int colB = blockIdx.y * 128;
  const int wm = (wave & 1) * 64, wn = (wave >> 1) * 64;
  const int fr = lane & 15;
  const int q = lane >> 4, lx = lane & 7;
  const int offK0 = (q ^ lx) << 3, offK1 = ((q + 4) ^ lx) << 3;

  for (int i = t; i < 4096; i += 256) W1s[(i >> 6) * 72 + (i & 63)] = W1B[i];
  for (int i = t; i < 5120; i += 256) A2s[(i >> 6) * 72 + (i & 63)] = A2B[i];
  if (t < 64) { HBs[t] = HBv[t]; Wrs[t] = W_read[t]; }
  const float pw = prelu_w[0];
  const float br = b_read[0];

  f32x4 acc[4][4];
  const f32x4 zero = {0.f, 0.f, 0.f, 0.f};
#pragma unroll
  for (int i = 0; i < 4; ++i)
#pragma unroll
    for (int j = 0; j < 4; ++j) acc[i][j] = zero;

  // loop-carried staging pointers
  const bf16* aSrc[4]; const bf16* bSrc[4];
  uint32_t* aDst[4]; uint32_t* bDst[4];
#pragma unroll
  for (int j = 0; j < 4; ++j) {
    int c = t + 256 * j;
    int row = c >> 3;
    int qs = (c & 7) ^ (row & 7);
    aSrc[j] = Y + (size_t)(rowA + row) * 2048 + qs * 8;
    bSrc[j] = ADJB + (size_t)(colB + row) * 1024 + qs * 8;
    aDst[j] = (uint32_t*)&sm.st.As[c * 8];
    bDst[j] = (uint32_t*)&sm.st.Bs[c * 8];
  }
  int rAb[4], rBb[4];
#pragma unroll
  for (int i = 0; i < 4; ++i) {
    rAb[i] = (wm + i * 16 + fr) * 64;
    rBb[i] = (wn + i * 16 + fr) * 64;
  }
  __syncthreads();

  for (int s = 0; s < 2; ++s) {
    for (int kk = 0; kk < 1024; kk += 64) {
#pragma unroll
      for (int j = 0; j < 4; ++j) {
        __builtin_amdgcn_global_load_lds((const uint32_t*)aSrc[j], aDst[j], 16, 0, 0);
        aSrc[j] += 64;
      }
#pragma unroll
      for (int j = 0; j < 4; ++j) {
        __builtin_amdgcn_global_load_lds((const uint32_t*)bSrc[j], bDst[j], 16, 0, 0);
        bSrc[j] += 64;
      }
      __syncthreads();
#pragma unroll
      for (int k2 = 0; k2 < 2; ++k2) {
        const int off = k2 ? offK1 : offK0;
        bf16x8_t af[4], bfr[4];
#pragma unroll
        for (int i = 0; i < 4; ++i)
          af[i] = *reinterpret_cast<const bf16x8_t*>(&sm.st.As[rAb[i] + off]);
#pragma unroll
        for (int i = 0; i < 4; ++i)
          bfr[i] = *reinterpret_cast<const bf16x8_t*>(&sm.st.Bs[rBb[i] + off]);
#pragma unroll
        for (int i = 0; i < 4; ++i)
#pragma unroll
          for (int j = 0; j < 4; ++j)
            acc[i][j] = __builtin_amdgcn_mfma_f32_16x16x32_bf16(af[i], bfr[j], acc[i][j], 0, 0, 0);
      }
      __syncthreads();
    }
    if (s == 0) {
#pragma unroll
      for (int j = 0; j < 4; ++j) bSrc[j] += (1024 * 1024 - 1024);
    }
  }

  // ---- phase 2a: gc tile -> LDS bf16, layout [b2][w_local][c] pad 72 ----
  {
    const int b2w = wm >> 6;
#pragma unroll
    for (int i = 0; i < 4; ++i) {
      const int cc0 = i * 16 + q * 4;
#pragma unroll
      for (int j = 0; j < 4; ++j) {
        const int wl = wn + j * 16 + fr;
        bf16x4_t r;
        r.x = (bf16)acc[i][j][0]; r.y = (bf16)acc[i][j][1];
        r.z = (bf16)acc[i][j][2]; r.w = (bf16)acc[i][j][3];
        *reinterpret_cast<bf16x4_t*>(&sm.gcs[b2w * 9216 + wl * 72 + cc0]) = r;
      }
    }
  }
  __syncthreads();

  const int b2 = wave >> 1, jh = wave & 1;
  const int b = blockIdx.x * 2 + b2;

  f32x4 acc2[5][4];
#pragma unroll
  for (int i = 0; i < 5; ++i)
#pragma unroll
    for (int j = 0; j < 4; ++j) {
      if (i < 4) {
        f32x4 c0;
#pragma unroll
        for (int r = 0; r < 4; ++r) c0[r] = HBs[i * 16 + q * 4 + r];
        acc2[i][j] = c0;
      } else {
        acc2[i][j] = zero;
      }
    }

  // phase 2b: W1 @ gc
#pragma unroll
  for (int k2 = 0; k2 < 64; k2 += 32) {
    bf16x8_t af2[4], bf2[4];
#pragma unroll
    for (int i = 0; i < 4; ++i)
      af2[i] = *reinterpret_cast<const bf16x8_t*>(&W1s[(i * 16 + fr) * 72 + k2 + q * 8]);
#pragma unroll
    for (int j = 0; j < 4; ++j)
      bf2[j] = *reinterpret_cast<const bf16x8_t*>(&sm.gcs[b2 * 9216 + (jh * 64 + j * 16 + fr) * 72 + k2 + q * 8]);
#pragma unroll
    for (int i = 0; i < 4; ++i)
#pragma unroll
      for (int j = 0; j < 4; ++j)
        acc2[i][j] = __builtin_amdgcn_mfma_f32_16x16x32_bf16(af2[i], bf2[j], acc2[i][j], 0, 0, 0);
  }

  // phase 3: [W2; W_read] @ h  — B-frags direct from swizzled HT global
#pragma unroll
  for (int k2 = 0; k2 < 64; k2 += 32) {
    const int off = k2 ? offK1 : offK0;  // (kq ^ (w&7))*8 with w&7 == lx
    bf16x8_t bh[4], af3[5];
#pragma unroll
    for (int j = 0; j < 4; ++j) {
      const int w = colB + jh * 64 + j * 16 + fr;
      bh[j] = *reinterpret_cast<const bf16x8_t*>(&HT[((size_t)(b << 10) + w) * 64 + off]);
    }
#pragma unroll
    for (int i = 0; i < 5; ++i)
      af3[i] = *reinterpret_cast<const bf16x8_t*>(&A2s[(i * 16 + fr) * 72 + k2 + q * 8]);
#pragma unroll
    for (int i = 0; i < 5; ++i)
#pragma unroll
      for (int j = 0; j < 4; ++j)
        acc2[i][j] = __builtin_amdgcn_mfma_f32_16x16x32_bf16(af3[i], bh[j], acc2[i][j], 0, 0, 0);
  }

  // epilogue: PReLU, write out2[b][0..63], reduce read output
  float rd[4] = {0.f, 0.f, 0.f, 0.f};
#pragma unroll
  for (int i = 0; i < 4; ++i) {
#pragma unroll
    for (int r = 0; r < 4; ++r) {
      const int o = i * 16 + q * 4 + r;
      const float wr = Wrs[o];
#pragma unroll
      for (int j = 0; j < 4; ++j) {
        const int wg = colB + jh * 64 + j * 16 + fr;
        float val = acc2[i][j][r];
        val = val >= 0.f ? val : pw * val;
        out2[(size_t)(b * 128 + o) * 1024 + wg] = val;
        rd[j] += wr * val;
      }
    }
  }
#pragma unroll
  for (int j = 0; j < 4; ++j) {
    rd[j] += __shfl_xor(rd[j], 16, 64);
    rd[j] += __shfl_xor(rd[j], 32, 64);
  }
  if (lane < 16) {
#pragma unroll
    for (int j = 0; j < 4; ++j) {
      const int wg = colB + jh * 64 + j * 16 + lane;
      out0[(size_t)b * 1024 + wg] = rd[j] + acc2[4][j][0] + br;
    }
  }
}

// ---------------------------------------------------------------------------
extern "C" void kernel_launch(void* const* d_in, const int* in_sizes, int n_in,
                              void* d_out, int out_size, void* d_ws, size_t ws_size,
                              hipStream_t stream) {
  (void)in_sizes; (void)n_in; (void)out_size; (void)ws_size;
  const float* x       = (const float*)d_in[0];
  const float* m       = (const float*)d_in[1];
  const float* u       = (const float*)d_in[2];
  const float* h       = (const float*)d_in[3];
  const float* adj     = (const float*)d_in[4];
  const float* W_in    = (const float*)d_in[5];
  const float* b_in    = (const float*)d_in[6];
  const float* W_gc    = (const float*)d_in[7];
  const float* b_gc    = (const float*)d_in[8];
  const float* W_out   = (const float*)d_in[9];
  const float* b_out   = (const float*)d_in[10];
  const float* W_read  = (const float*)d_in[11];
  const float* b_read  = (const float*)d_in[12];
  const float* prelu_w = (const float*)d_in[13];

  char* ws = (char*)d_ws;
  bf16*  Y    = (bf16*)(ws);                       // 33554432 B
  bf16*  ADJB = (bf16*)(ws + 33554432);            //  4194304 -> 37748736
  bf16*  HT   = (bf16*)(ws + 37748736);            // 16777216 -> 54525952
  bf16*  WAT  = (bf16*)(ws + 54525952);            //    16384 -> 54542336
  float* WYX  = (float*)(ws + 54542336);           //     2048 -> 54544384
  float* BIAS = (float*)(ws + 54544384);           //      512 -> 54544896
  bf16*  W1B  = (bf16*)(ws + 54544896);            //     8192 -> 54553088
  bf16*  A2B  = (bf16*)(ws + 54553088);            //    10240 -> 54563328
  float* HBv  = (float*)(ws + 54563328);           //      256 -> 54563584

  float* out0 = (float*)d_out;           // read  [B,1,N]  = 131072 f32
  float* out2 = out0 + 131072;           // out2  [B,128,N] f32

  hipLaunchKernelGGL(k_prep,  dim3(2119),     dim3(256), 0, stream,
                     adj, W_in, b_in, W_gc, b_gc, W_out, b_out, W_read,
                     ADJB, WAT, WYX, BIAS, W1B, A2B, HBv);
  hipLaunchKernelGGL(k_build, dim3(8, 128),   dim3(256), 0, stream,
                     x, m, u, h, WAT, WYX, BIAS, Y, HT, out2);
  hipLaunchKernelGGL(k_gemm,  dim3(64, 8),    dim3(256), 0, stream,
                     Y, ADJB, HT, W1B, A2B, HBv, W_read, b_read, prelu_w, out0, out2);
}